// Round 2
// baseline (16087.273 us; speedup 1.0000x reference)
//
#include <hip/hip_runtime.h>
#include <math.h>

#define B_    32
#define LQ    512
#define CIN_  21
#define COUT_ 21
#define D_    512
#define H_    8
#define E_    64
#define M_    64
#define DFF_  2048
#define MARK_ 4
#define KWIN  25
#define PW    12
#define LF    257
#define PRED_ 256
#define EPS_  1e-5f

static __device__ __forceinline__ int iclamp(int v, int lo, int hi) {
  return v < lo ? lo : (v > hi ? hi : v);
}

// ---------------------------------------------------------------- DFT tables
__global__ void k_dft_tables(float* __restrict__ cosF, float* __restrict__ negsinF,
                             float* __restrict__ c512, float* __restrict__ s512) {
  int i = blockIdx.x * 256 + threadIdx.x;
  if (i < 512) {
    float th = (float)i * (6.283185307179586f / 512.0f);
    c512[i] = cosf(th);
    s512[i] = sinf(th);
  }
  if (i >= 512 * LF) return;
  int t = i / LF, f = i % LF;
  int r = (t * f) & 511;                     // exact phase reduction
  float th = (float)r * (6.283185307179586f / 512.0f);
  cosF[i] = cosf(th);
  negsinF[i] = -sinf(th);
}

// ------------------------------------------- x_enc stats: low_init/high_init
__global__ void k_enc_decomp(const float* __restrict__ x,
                             float* __restrict__ lowi, float* __restrict__ highi) {
  int b = blockIdx.x, c = threadIdx.x;
  if (c >= CIN_) return;
  const float* xb = x + (long)b * LQ * CIN_ + c;
  float s = 0.f;
  for (int t = 0; t < LQ; t++) s += xb[(long)t * CIN_];
  float mean = s / (float)LQ;
  for (int t = 256; t < LQ; t++) {
    float w = 0.f;
    for (int j = t - PW; j <= t + PW; j++) {
      int jj = iclamp(j, 0, LQ - 1);
      w += xb[(long)jj * CIN_];
    }
    float m = w * (1.f / KWIN);
    lowi [((long)b * LQ + (t - 256)) * CIN_ + c] = m;
    highi[((long)b * LQ + (t - 256)) * CIN_ + c] = xb[(long)t * CIN_] - m;
  }
  for (int t = 256; t < LQ; t++) {
    lowi [((long)b * LQ + t) * CIN_ + c] = mean;
    highi[((long)b * LQ + t) * CIN_ + c] = 0.f;
  }
}

// ----------------------------------------------------------------- embedding
__global__ void k_embed(const float* __restrict__ x, const float* __restrict__ mark,
                        const float* __restrict__ ck, const float* __restrict__ tw,
                        float* __restrict__ out) {
  int o = blockIdx.x * 256 + threadIdx.x;   // < D
  int t = blockIdx.y, b = blockIdx.z;
  float acc = 0.f;
  const float* xb = x + (long)b * LQ * CIN_;
  #pragma unroll
  for (int j = 0; j < 3; j++) {
    int tt = (t + j - 1 + LQ) & (LQ - 1);
    const float* xr = xb + (long)tt * CIN_;
    const float* kr = ck + (long)(j * CIN_) * D_ + o;
    for (int c = 0; c < CIN_; c++) acc = fmaf(xr[c], kr[(long)c * D_], acc);
  }
  const float* mr = mark + ((long)b * LQ + t) * MARK_;
  #pragma unroll
  for (int mm = 0; mm < MARK_; mm++) acc = fmaf(mr[mm], tw[(long)mm * D_ + o], acc);
  out[((long)b * LQ + t) * D_ + o] = acc;
}

// ------------------------------------------------------------------ fp32 GEMM
// C = act(A * Bm + bias); A: [Mr,Kd] row-major, Bm: [Kd,Nd]
template<int ACT>
__global__ __launch_bounds__(256) void k_gemm(
    const float* __restrict__ A, const float* __restrict__ Bm,
    const float* __restrict__ bias, float* __restrict__ C,
    int Mr, int Nd, int Kd, int lda) {
  __shared__ float As[32][64];
  __shared__ float Bs[32][64];
  int m0 = blockIdx.y * 64, n0 = blockIdx.x * 64;
  int tid = threadIdx.x;
  int tx = tid & 15, ty = tid >> 4;
  float acc[4][4] = {};
  for (int k0 = 0; k0 < Kd; k0 += 32) {
    {
      int kk = tid & 31, mm0 = tid >> 5;
      #pragma unroll
      for (int r = 0; r < 8; r++) {
        int mm = mm0 + r * 8;
        int gm = m0 + mm, gk = k0 + kk;
        As[kk][mm] = (gm < Mr) ? A[(long)gm * lda + gk] : 0.f;
      }
    }
    {
      int nn = tid & 63, kk0 = tid >> 6;
      #pragma unroll
      for (int r = 0; r < 8; r++) {
        int kk = kk0 + r * 4;
        int gn = n0 + nn, gk = k0 + kk;
        Bs[kk][nn] = (gn < Nd) ? Bm[(long)gk * Nd + gn] : 0.f;
      }
    }
    __syncthreads();
    #pragma unroll
    for (int kk = 0; kk < 32; kk++) {
      float av[4], bv[4];
      #pragma unroll
      for (int i = 0; i < 4; i++) av[i] = As[kk][ty * 4 + i];
      #pragma unroll
      for (int j = 0; j < 4; j++) bv[j] = Bs[kk][tx * 4 + j];
      #pragma unroll
      for (int i = 0; i < 4; i++)
        #pragma unroll
        for (int j = 0; j < 4; j++)
          acc[i][j] = fmaf(av[i], bv[j], acc[i][j]);
    }
    __syncthreads();
  }
  #pragma unroll
  for (int i = 0; i < 4; i++) {
    int gm = m0 + ty * 4 + i;
    if (gm >= Mr) continue;
    #pragma unroll
    for (int j = 0; j < 4; j++) {
      int gn = n0 + tx * 4 + j;
      if (gn >= Nd) continue;
      float v = acc[i][j];
      if (bias) v += bias[gn];
      if (ACT == 1) {   // jax.nn.gelu approximate=True
        float xx = v;
        float x3 = xx * xx * xx;
        float th = tanhf(0.7978845608028654f * (xx + 0.044715f * x3));
        v = 0.5f * xx * (1.f + th);
      }
      C[(long)gm * Nd + gn] = v;
    }
  }
}

// ----------------------------------------------------------------- utilities
__global__ void k_zero(float* __restrict__ p, int n) {
  int i = blockIdx.x * 256 + threadIdx.x;
  if (i < n) p[i] = 0.f;
}

// --------------- DFT + |.| epilogue -> amp[f] (no spectrum materialization)
// rows r = b*512 + d; xf[r,f] = sum_t X[b,t,d] * e^{-2 pi i f t/512}
__global__ __launch_bounds__(256) void k_specamp(
    const float* __restrict__ X, const float* __restrict__ cosT,
    const float* __restrict__ nsinT, float* __restrict__ amp) {
  int m0 = blockIdx.y * 64, n0 = blockIdx.x * 64;
  int tid = threadIdx.x, tx = tid & 15, ty = tid >> 4;
  __shared__ float As[32][64];
  __shared__ float Cs[32][65];
  __shared__ float Ss[32][65];
  float aR[4][4] = {}, aI[4][4] = {};
  int b = m0 >> 9, d0 = m0 & 511;
  const float* Xb = X + (long)b * LQ * D_ + d0;
  for (int k0 = 0; k0 < 512; k0 += 32) {
    {
      int mm = tid & 63, kk0 = tid >> 6;
      #pragma unroll
      for (int r = 0; r < 8; r++) {
        int kk = kk0 + r * 4;
        As[kk][mm] = Xb[(long)(k0 + kk) * D_ + mm];
      }
    }
    {
      int nn = tid & 63, kk0 = tid >> 6;
      #pragma unroll
      for (int r = 0; r < 8; r++) {
        int kk = kk0 + r * 4;
        int gn = n0 + nn;
        float c = 0.f, s = 0.f;
        if (gn < LF) { long a = (long)(k0 + kk) * LF + gn; c = cosT[a]; s = nsinT[a]; }
        Cs[kk][nn] = c; Ss[kk][nn] = s;
      }
    }
    __syncthreads();
    #pragma unroll
    for (int kk = 0; kk < 32; kk++) {
      float av[4], cv[4], sv[4];
      #pragma unroll
      for (int i = 0; i < 4; i++) av[i] = As[kk][ty * 4 + i];
      #pragma unroll
      for (int j = 0; j < 4; j++) { cv[j] = Cs[kk][tx * 4 + j]; sv[j] = Ss[kk][tx * 4 + j]; }
      #pragma unroll
      for (int i = 0; i < 4; i++)
        #pragma unroll
        for (int j = 0; j < 4; j++) {
          aR[i][j] = fmaf(av[i], cv[j], aR[i][j]);
          aI[i][j] = fmaf(av[i], sv[j], aI[i][j]);
        }
    }
    __syncthreads();
  }
  __shared__ float csum[64];
  if (tid < 64) csum[tid] = 0.f;
  __syncthreads();
  #pragma unroll
  for (int j = 0; j < 4; j++) {
    float s = 0.f;
    #pragma unroll
    for (int i = 0; i < 4; i++) s += sqrtf(aR[i][j] * aR[i][j] + aI[i][j] * aI[i][j]);
    atomicAdd(&csum[tx * 4 + j], s);
  }
  __syncthreads();
  if (tid < 64 && n0 + tid < LF) atomicAdd(&amp[n0 + tid], csum[tid]);
}

// stable descending top-64 of amp[257] (ties -> lower index, like lax.top_k)
__global__ void k_topk(const float* __restrict__ amp, int* __restrict__ idx) {
  __shared__ float v[512];
  __shared__ float rv[512];
  __shared__ int   ri[512];
  int tid = threadIdx.x;          // 512 threads
  v[tid] = (tid < LF) ? amp[tid] : -INFINITY;
  __syncthreads();
  for (int k = 0; k < M_; k++) {
    rv[tid] = v[tid]; ri[tid] = tid;
    __syncthreads();
    for (int st = 256; st > 0; st >>= 1) {
      if (tid < st) {
        float a = rv[tid], b = rv[tid + st];
        int ai = ri[tid], bi = ri[tid + st];
        if (b > a || (b == a && bi < ai)) { rv[tid] = b; ri[tid] = bi; }
      }
      __syncthreads();
    }
    if (tid == 0) { idx[k] = ri[0]; v[ri[0]] = -INFINITY; }
    __syncthreads();
  }
}

// ------------- direct DFT at the 64 selected freqs -> gR/gI [(b*H+h)*E+e][64]
__global__ __launch_bounds__(256) void k_gatherdft(
    const float* __restrict__ X, const float* __restrict__ cosT,
    const float* __restrict__ nsinT, const int* __restrict__ idx,
    float* __restrict__ gR, float* __restrict__ gI) {
  int m0 = blockIdx.x * 64;
  int tid = threadIdx.x, tx = tid & 15, ty = tid >> 4;
  __shared__ float As[32][64];
  __shared__ float Cs[32][65];
  __shared__ float Ss[32][65];
  __shared__ int fsel[64];
  if (tid < 64) fsel[tid] = idx[tid];
  __syncthreads();
  float aR[4][4] = {}, aI[4][4] = {};
  int b = m0 >> 9, d0 = m0 & 511;
  const float* Xb = X + (long)b * LQ * D_ + d0;
  for (int k0 = 0; k0 < 512; k0 += 32) {
    {
      int mm = tid & 63, kk0 = tid >> 6;
      #pragma unroll
      for (int r = 0; r < 8; r++) {
        int kk = kk0 + r * 4;
        As[kk][mm] = Xb[(long)(k0 + kk) * D_ + mm];
      }
    }
    {
      int nn = tid & 63, kk0 = tid >> 6;
      int f = fsel[nn];
      #pragma unroll
      for (int r = 0; r < 8; r++) {
        int kk = kk0 + r * 4;
        long a = (long)(k0 + kk) * LF + f;
        Cs[kk][nn] = cosT[a]; Ss[kk][nn] = nsinT[a];
      }
    }
    __syncthreads();
    #pragma unroll
    for (int kk = 0; kk < 32; kk++) {
      float av[4], cv[4], sv[4];
      #pragma unroll
      for (int i = 0; i < 4; i++) av[i] = As[kk][ty * 4 + i];
      #pragma unroll
      for (int j = 0; j < 4; j++) { cv[j] = Cs[kk][tx * 4 + j]; sv[j] = Ss[kk][tx * 4 + j]; }
      #pragma unroll
      for (int i = 0; i < 4; i++)
        #pragma unroll
        for (int j = 0; j < 4; j++) {
          aR[i][j] = fmaf(av[i], cv[j], aR[i][j]);
          aI[i][j] = fmaf(av[i], sv[j], aI[i][j]);
        }
    }
    __syncthreads();
  }
  #pragma unroll
  for (int i = 0; i < 4; i++) {
    long row = m0 + ty * 4 + i;
    #pragma unroll
    for (int j = 0; j < 4; j++) {
      gR[row * 64 + tx * 4 + j] = aR[i][j];
      gI[row * 64 + tx * 4 + j] = aI[i][j];
    }
  }
}

// ------------------- outs[b,h,o,m] = sum_e src[b,h,e,m] * w[h,e,o,m] (complex)
__global__ __launch_bounds__(256) void k_modemix(
    const float* __restrict__ sre, const float* __restrict__ sim,
    const float* __restrict__ wre, const float* __restrict__ wim,
    float* __restrict__ ore, float* __restrict__ oim) {
  int b = blockIdx.z, h = blockIdx.y, oc = blockIdx.x;
  int m = threadIdx.x, osub = threadIdx.y;
  int o = oc * 4 + osub;
  __shared__ float xr[E_][M_], xi[E_][M_];
  #pragma unroll
  for (int r = 0; r < 16; r++) {
    int e = r * 4 + osub;
    long a = ((long)(b * H_ + h) * E_ + e) * M_ + m;
    xr[e][m] = sre[a]; xi[e][m] = sim[a];
  }
  __syncthreads();
  float ar = 0.f, ai = 0.f;
  const float* wrb = wre + ((long)(h * E_) * E_ + o) * M_ + m;
  const float* wib = wim + ((long)(h * E_) * E_ + o) * M_ + m;
  #pragma unroll 4
  for (int e = 0; e < E_; e++) {
    float wr = wrb[(long)e * E_ * M_], wi = wib[(long)e * E_ * M_];
    float qr = xr[e][m], qi = xi[e][m];
    ar = fmaf(qr, wr, ar); ar = fmaf(-qi, wi, ar);
    ai = fmaf(qr, wi, ai); ai = fmaf(qi, wr, ai);
  }
  long oaddr = ((long)(b * H_ + h) * E_ + o) * M_ + m;
  ore[oaddr] = ar; oim[oaddr] = ai;
}

// --------------- sparse irfft of 64 modes, writes [B,L,D] layout (d = h*E+o)
__global__ __launch_bounds__(512) void k_irfft(
    const float* __restrict__ ore, const float* __restrict__ oim,
    const int* __restrict__ idx, const float* __restrict__ c512,
    const float* __restrict__ s512, float scale, float* __restrict__ out) {
  int d = blockIdx.x, b = blockIdx.y, t = threadIdx.x;
  int h = d >> 6, o = d & 63;
  __shared__ float mr[M_], mi[M_];
  __shared__ int   mf[M_];
  __shared__ float cs[512], sn[512];
  cs[t] = c512[t]; sn[t] = s512[t];
  if (t < M_) {
    long a = ((long)(b * H_ + h) * E_ + o) * M_ + t;
    int f = idx[t];
    mf[t] = f;
    float c = (f == 0 || f == 256) ? 1.f : 2.f;   // DC / Nyquist: no doubling
    mr[t] = ore[a] * c; mi[t] = oim[a] * c;
  }
  __syncthreads();
  float acc = 0.f;
  #pragma unroll 8
  for (int m = 0; m < M_; m++) {
    int r = (mf[m] * t) & 511;
    acc += mr[m] * cs[r] - mi[m] * sn[r];   // Re(X * e^{+i th})
  }
  out[((long)b * LQ + t) * D_ + d] = acc * scale;
}

// ---------------------------------------- series_decomp (direct 25-window)
// s = a (+ bsrc); season = s - movmean(s); trend: 0 none, 1 write, 2 accumulate
__global__ void k_decomp(const float* __restrict__ a, const float* __restrict__ bsrc,
                         float* __restrict__ season, float* __restrict__ trend,
                         int trendMode) {
  int c = blockIdx.x * 256 + threadIdx.x;
  int t = blockIdx.y, b = blockIdx.z;
  long base = (long)b * LQ * D_ + c;
  float s = 0.f;
  #pragma unroll
  for (int j = -PW; j <= PW; j++) {
    int tt = iclamp(t + j, 0, LQ - 1);
    float v = a[base + (long)tt * D_];
    if (bsrc) v += bsrc[base + (long)tt * D_];
    s += v;
  }
  float m = s * (1.f / KWIN);
  float cur = a[base + (long)t * D_];
  if (bsrc) cur += bsrc[base + (long)t * D_];
  season[base + (long)t * D_] = cur - m;
  if (trendMode == 1) trend[base + (long)t * D_] = m;
  else if (trendMode == 2) trend[base + (long)t * D_] += m;
}

// ------------------------------------------------------------- layernorm ops
__global__ __launch_bounds__(256) void k_ln(const float* __restrict__ x,
                                            const float* __restrict__ g,
                                            const float* __restrict__ bt,
                                            float* __restrict__ out) {
  long row = blockIdx.x;
  const float* xr = x + row * D_;
  float v1 = xr[threadIdx.x], v2 = xr[threadIdx.x + 256];
  __shared__ float rs[256], rq[256];
  rs[threadIdx.x] = v1 + v2;
  rq[threadIdx.x] = v1 * v1 + v2 * v2;
  __syncthreads();
  for (int st = 128; st > 0; st >>= 1) {
    if (threadIdx.x < st) { rs[threadIdx.x] += rs[threadIdx.x + st]; rq[threadIdx.x] += rq[threadIdx.x + st]; }
    __syncthreads();
  }
  float mu = rs[0] / (float)D_;
  float var = fmaxf(rq[0] / (float)D_ - mu * mu, 0.f);
  float inv = rsqrtf(var + EPS_);
  out[row * D_ + threadIdx.x]       = (v1 - mu) * inv * g[threadIdx.x]       + bt[threadIdx.x];
  out[row * D_ + threadIdx.x + 256] = (v2 - mu) * inv * g[threadIdx.x + 256] + bt[threadIdx.x + 256];
}

__global__ void k_tmsub(const float* __restrict__ x, float* __restrict__ out) {
  int dcol = blockIdx.x * 256 + threadIdx.x, b = blockIdx.y;
  long base = (long)b * LQ * D_ + dcol;
  float s = 0.f;
  for (int t = 0; t < LQ; t++) s += x[base + (long)t * D_];
  float mu = s / (float)LQ;
  for (int t = 0; t < LQ; t++) out[base + (long)t * D_] = x[base + (long)t * D_] - mu;
}

// ---------------------------------------- cross attn: qk = ctanh(qs . ks)
// inputs gathered: q/k [(b*H+h)*E+e][64]
__global__ __launch_bounds__(256) void k_qk(
    const float* __restrict__ qR, const float* __restrict__ qI,
    const float* __restrict__ kR, const float* __restrict__ kI,
    float* __restrict__ qkre, float* __restrict__ qkim) {  // [b,h,y,x]
  int b = blockIdx.z, h = blockIdx.y, xc = blockIdx.x;
  int y = threadIdx.x, xs4 = threadIdx.y;
  __shared__ float ksr[E_][64], ksi[E_][64];
  __shared__ float qsr[E_][16], qsi[E_][16];
  long base = (long)(b * H_ + h) * E_;
  int tid = threadIdx.y * 64 + threadIdx.x;
  #pragma unroll
  for (int r = 0; r < 16; r++) {
    int e = r * 4 + xs4;
    long a = (base + e) * 64 + y;
    ksr[e][y] = kR[a]; ksi[e][y] = kI[a];
  }
  #pragma unroll
  for (int r = 0; r < 4; r++) {
    int ii = tid + r * 256;
    int e = ii >> 4, xl = ii & 15;
    long a = (base + e) * 64 + xc * 16 + xl;
    qsr[e][xl] = qR[a]; qsi[e][xl] = qI[a];
  }
  __syncthreads();
  #pragma unroll
  for (int xi = 0; xi < 4; xi++) {
    int xl = xs4 * 4 + xi;
    float ar = 0.f, ai = 0.f;
    for (int e = 0; e < E_; e++) {
      float a1 = qsr[e][xl], b1 = qsi[e][xl], c1 = ksr[e][y], d1 = ksi[e][y];
      ar += a1 * c1 - b1 * d1;
      ai += a1 * d1 + b1 * c1;
    }
    float s = tanhf(ar), t = tanf(ai);
    float t2 = t * t;
    float den = 1.f + s * s * t2;
    float outr = s * (1.f + t2) / den;
    float outi = t * (1.f - s * s) / den;
    int x = xc * 16 + xl;
    long oa = ((long)(b * H_ + h) * M_ + y) * M_ + x;
    qkre[oa] = outr; qkim[oa] = outi;
  }
}

// qkv[b,h,e,x] = sum_y qk[b,h,x,y] * ks[b,h,e,y]  (ks gathered)
__global__ __launch_bounds__(256) void k_qkv(
    const float* __restrict__ qkre, const float* __restrict__ qkim,   // [b,h,y,x]
    const float* __restrict__ kR, const float* __restrict__ kI,
    float* __restrict__ vre, float* __restrict__ vim) {               // [b,h,e,x]
  int b = blockIdx.z, h = blockIdx.y, ec = blockIdx.x;
  int x = threadIdx.x, es = threadIdx.y;
  int e = ec * 4 + es;
  __shared__ float qr[M_][M_], qi2[M_][M_];
  int tid = threadIdx.y * 64 + threadIdx.x;
  #pragma unroll
  for (int r = 0; r < 16; r++) {
    int ii = tid + r * 256;
    int yy = ii >> 6, xx = ii & 63;
    long a = ((long)(b * H_ + h) * M_ + yy) * M_ + xx;
    qr[yy][xx] = qkre[a]; qi2[yy][xx] = qkim[a];
  }
  __syncthreads();
  float ar = 0.f, ai = 0.f;
  long kbase = ((long)(b * H_ + h) * E_ + e) * 64;
  for (int y = 0; y < M_; y++) {
    float c1 = kR[kbase + y], d1 = kI[kbase + y];
    float a1 = qr[y][x], b1 = qi2[y][x];
    ar += a1 * c1 - b1 * d1;
    ai += a1 * d1 + b1 * c1;
  }
  long o = ((long)(b * H_ + h) * E_ + e) * M_ + x;
  vre[o] = ar; vim[o] = ai;
}

// ---------------------------------------------------------------- final fuse
__global__ __launch_bounds__(256) void k_final(
    const float* __restrict__ lowi, const float* __restrict__ tsum,
    const float* __restrict__ tp, const float* __restrict__ ln3,
    const float* __restrict__ projW, const float* __restrict__ projb,
    float* __restrict__ out) {
  int o = threadIdx.x;                         // 0..31 (21 active)
  int rowi = blockIdx.x * 8 + threadIdx.y;     // 0..8191
  int b = rowi >> 8, tpi = rowi & 255;
  int t = tpi + 256;
  if (o >= COUT_) return;
  float acc = lowi[((long)b * LQ + t) * CIN_ + o] + projb[o];
  #pragma unroll
  for (int j = 0; j < 3; j++) {
    int tt = (t + j - 1 + LQ) & (LQ - 1);
    const float* xr = tsum + ((long)b * LQ + tt) * D_;
    const float* kr = tp + (long)(j * D_) * COUT_ + o;
    for (int c = 0; c < D_; c++) acc = fmaf(xr[c], kr[(long)c * COUT_], acc);
  }
  const float* lr = ln3 + ((long)b * LQ + t) * D_;
  for (int d0 = 0; d0 < D_; d0++) acc = fmaf(lr[d0], projW[(long)d0 * COUT_ + o], acc);
  out[((long)b * PRED_ + tpi) * COUT_ + o] = acc;
}

// ============================================================================
extern "C" void kernel_launch(void* const* d_in, const int* in_sizes, int n_in,
                              void* d_out, int out_size, void* d_ws, size_t ws_size,
                              hipStream_t stream) {
  const float* x_enc      = (const float*)d_in[0];
  const float* x_mark_enc = (const float*)d_in[1];
  const float* x_mark_dec = (const float*)d_in[3];
  const float* emb_enc_k  = (const float*)d_in[4];
  const float* emb_enc_t  = (const float*)d_in[5];
  const float* emb_dec_k  = (const float*)d_in[6];
  const float* emb_dec_t  = (const float*)d_in[7];
  const float* fw_enc_re  = (const float*)d_in[8];
  const float* fw_enc_im  = (const float*)d_in[9];
  const float* fw_dec_re  = (const float*)d_in[10];
  const float* fw_dec_im  = (const float*)d_in[11];
  const float* fw_cr_re   = (const float*)d_in[12];
  const float* fw_cr_im   = (const float*)d_in[13];
  const float* enc_Wq     = (const float*)d_in[14];
  const float* enc_bq     = (const float*)d_in[15];
  const float* enc_Wo     = (const float*)d_in[16];
  const float* enc_bo     = (const float*)d_in[17];
  const float* enc_c1     = (const float*)d_in[18];
  const float* enc_c2     = (const float*)d_in[19];
  const float* enc_ng     = (const float*)d_in[20];
  const float* enc_nb     = (const float*)d_in[21];
  const float* ds_Wq      = (const float*)d_in[22];
  const float* ds_bq      = (const float*)d_in[23];
  const float* ds_Wo      = (const float*)d_in[24];
  const float* ds_bo      = (const float*)d_in[25];
  const float* dc_Wq      = (const float*)d_in[26];
  const float* dc_bq      = (const float*)d_in[27];
  const float* dc_Wk      = (const float*)d_in[28];
  const float* dc_bk      = (const float*)d_in[29];
  const float* dc_Wo      = (const float*)d_in[30];
  const float* dc_bo      = (const float*)d_in[31];
  const float* dec_c1     = (const float*)d_in[32];
  const float* dec_c2     = (const float*)d_in[33];
  const float* dec_tp     = (const float*)d_in[34];
  const float* dec_ng     = (const float*)d_in[35];
  const float* dec_nb     = (const float*)d_in[36];
  const float* proj_W     = (const float*)d_in[37];
  const float* proj_b     = (const float*)d_in[38];
  float* out = (float*)d_out;
  float* ws  = (float*)d_ws;

  // ---- workspace layout (floats); total ~= 47.1M floats ~= 189 MB
  constexpr size_t BIG = (size_t)B_ * LQ * D_;      // 8388608
  constexpr size_t OUS = (size_t)B_ * H_ * E_ * M_; // 1048576
  constexpr int    FCH = 2048;                      // FFN row-chunk
  size_t o = 0;
  auto nxt = [&](size_t n) { size_t r = o; o += (n + 255) & ~(size_t)255; return r; };
  size_t oA = nxt(BIG), oB = nxt(BIG), oC = nxt(BIG), oTS = nxt(BIG);
  size_t oFF = nxt((size_t)FCH * DFF_);
  size_t oQSR = nxt(OUS), oQSI = nxt(OUS), oKSR = nxt(OUS), oKSI = nxt(OUS),
         oOR = nxt(OUS), oOI = nxt(OUS), oQKR = nxt(OUS), oQKI = nxt(OUS);
  size_t oCOS = nxt((size_t)512 * LF), oNSN = nxt((size_t)512 * LF);
  size_t oC5 = nxt(512), oS5 = nxt(512);
  size_t oAMP = nxt(512), oIQ = nxt(64), oIK = nxt(64);
  size_t oLOW = nxt((size_t)B_ * LQ * CIN_), oHI = nxt((size_t)B_ * LQ * CIN_);
  (void)ws_size; (void)in_sizes; (void)n_in; (void)out_size;

  int* idxq = (int*)(ws + oIQ);
  int* idxk = (int*)(ws + oIK);

  auto GEMM = [&](const float* Ap, const float* Bp, const float* bias,
                  float* Cp, int Mr, int Nd, int Kd, int act) {
    dim3 g((Nd + 63) / 64, (Mr + 63) / 64, 1);
    if (act) k_gemm<1><<<g, dim3(256), 0, stream>>>(Ap, Bp, bias, Cp, Mr, Nd, Kd, Kd);
    else     k_gemm<0><<<g, dim3(256), 0, stream>>>(Ap, Bp, bias, Cp, Mr, Nd, Kd, Kd);
  };
  auto AMPSEL = [&](const float* x, int* idxp) {
    k_zero<<<2, 256, 0, stream>>>(ws + oAMP, 512);
    k_specamp<<<dim3(5, 256), 256, 0, stream>>>(x, ws + oCOS, ws + oNSN, ws + oAMP);
    k_topk<<<1, 512, 0, stream>>>(ws + oAMP, idxp);
  };
  auto GATHER = [&](const float* x, const int* idxp, float* gR, float* gI) {
    k_gatherdft<<<256, 256, 0, stream>>>(x, ws + oCOS, ws + oNSN, idxp, gR, gI);
  };
  auto MODEMIX = [&](const float* sR, const float* sI, const float* wre, const float* wim) {
    k_modemix<<<dim3(16, H_, B_), dim3(64, 4), 0, stream>>>(sR, sI, wre, wim, ws + oOR, ws + oOI);
  };
  auto IRFFT = [&](const int* idxp, float scale, float* dst) {
    k_irfft<<<dim3(D_, B_), 512, 0, stream>>>(ws + oOR, ws + oOI, idxp,
                                              ws + oC5, ws + oS5, scale, dst);
  };
  auto DECOMP = [&](const float* a, const float* bsrc, float* season, float* trend, int mode) {
    k_decomp<<<dim3(2, LQ, B_), 256, 0, stream>>>(a, bsrc, season, trend, mode);
  };
  auto FFNP = [&](const float* x, const float* c1, const float* c2, float* y) {
    for (int ch = 0; ch < (B_ * LQ) / FCH; ch++) {
      GEMM(x + (size_t)ch * FCH * D_, c1, nullptr, ws + oFF, FCH, DFF_, D_, 1);
      GEMM(ws + oFF, c2, nullptr, y + (size_t)ch * FCH * D_, FCH, D_, DFF_, 0);
    }
  };

  // ---- prologue
  k_dft_tables<<<(512 * LF + 255) / 256, 256, 0, stream>>>(ws + oCOS, ws + oNSN,
                                                           ws + oC5, ws + oS5);
  k_enc_decomp<<<B_, 32, 0, stream>>>(x_enc, ws + oLOW, ws + oHI);
  k_embed<<<dim3(2, LQ, B_), 256, 0, stream>>>(x_enc, x_mark_enc, emb_enc_k, emb_enc_t, ws + oA);

  // ---- encoder (enc lives in A; temporaries B, C)
  for (int i = 0; i < 2; i++) {
    GEMM(ws + oA, enc_Wq + (size_t)i * D_ * D_, enc_bq + (size_t)i * D_, ws + oB, B_ * LQ, D_, D_, 0);
    AMPSEL(ws + oB, idxq);
    GATHER(ws + oB, idxq, ws + oQSR, ws + oQSI);
    MODEMIX(ws + oQSR, ws + oQSI, fw_enc_re, fw_enc_im);
    IRFFT(idxq, 1.f / 512.f, ws + oB);
    GEMM(ws + oB, enc_Wo + (size_t)i * D_ * D_, enc_bo + (size_t)i * D_, ws + oC, B_ * LQ, D_, D_, 0);
    DECOMP(ws + oA, ws + oC, ws + oB, nullptr, 0);                       // x1 -> B
    FFNP(ws + oB, enc_c1 + (size_t)i * D_ * DFF_, enc_c2 + (size_t)i * DFF_ * D_, ws + oC);
    DECOMP(ws + oB, ws + oC, ws + oA, nullptr, 0);                       // enc -> A
  }
  k_ln<<<B_ * LQ, 256, 0, stream>>>(ws + oA, enc_ng, enc_nb, ws + oB);
  k_tmsub<<<dim3(2, B_), 256, 0, stream>>>(ws + oB, ws + oA);            // enc final -> A

  // ---- cross-K path (uses final enc, then enc buffer is free)
  GEMM(ws + oA, dc_Wk, dc_bk, ws + oB, B_ * LQ, D_, D_, 0);
  AMPSEL(ws + oB, idxk);
  GATHER(ws + oB, idxk, ws + oKSR, ws + oKSI);

  // ---- decoder (dec -> A)
  k_embed<<<dim3(2, LQ, B_), 256, 0, stream>>>(ws + oHI, x_mark_dec, emb_dec_k, emb_dec_t, ws + oA);
  GEMM(ws + oA, ds_Wq, ds_bq, ws + oB, B_ * LQ, D_, D_, 0);
  AMPSEL(ws + oB, idxq);
  GATHER(ws + oB, idxq, ws + oQSR, ws + oQSI);
  MODEMIX(ws + oQSR, ws + oQSI, fw_dec_re, fw_dec_im);
  IRFFT(idxq, 1.f / 512.f, ws + oB);
  GEMM(ws + oB, ds_Wo, ds_bo, ws + oC, B_ * LQ, D_, D_, 0);              // a -> C
  DECOMP(ws + oA, ws + oC, ws + oB, ws + oTS, 1);                        // x1 -> B, t1 -> TS

  GEMM(ws + oB, dc_Wq, dc_bq, ws + oC, B_ * LQ, D_, D_, 0);              // q -> C
  AMPSEL(ws + oC, idxq);
  GATHER(ws + oC, idxq, ws + oQSR, ws + oQSI);
  k_qk<<<dim3(4, H_, B_), dim3(64, 4), 0, stream>>>(
      ws + oQSR, ws + oQSI, ws + oKSR, ws + oKSI, ws + oQKR, ws + oQKI);
  k_qkv<<<dim3(16, H_, B_), dim3(64, 4), 0, stream>>>(
      ws + oQKR, ws + oQKI, ws + oKSR, ws + oKSI, ws + oQSR, ws + oQSI); // v -> qs bufs
  MODEMIX(ws + oQSR, ws + oQSI, fw_cr_re, fw_cr_im);
  IRFFT(idxq, 1.f / (512.f * 262144.f), ws + oC);
  GEMM(ws + oC, dc_Wo, dc_bo, ws + oA, B_ * LQ, D_, D_, 0);              // c -> A
  DECOMP(ws + oB, ws + oA, ws + oC, ws + oTS, 2);                        // x2 -> C, t2 +=
  FFNP(ws + oC, dec_c1, dec_c2, ws + oA);                                // y -> A
  DECOMP(ws + oC, ws + oA, ws + oB, ws + oTS, 2);                        // x3 -> B, t3 +=
  k_ln<<<B_ * LQ, 256, 0, stream>>>(ws + oB, dec_ng, dec_nb, ws + oA);
  k_tmsub<<<dim3(2, B_), 256, 0, stream>>>(ws + oA, ws + oC);            // ln3 -> C
  k_final<<<dim3(B_ * PRED_ / 8), dim3(32, 8), 0, stream>>>(
      ws + oLOW, ws + oTS, dec_tp, ws + oC, proj_W, proj_b, out);
}

// Round 4
// 10042.674 us; speedup vs baseline: 1.6019x; 1.6019x over previous
//
#include <hip/hip_runtime.h>
#include <math.h>

#define B_    32
#define LQ    512
#define CIN_  21
#define COUT_ 21
#define D_    512
#define H_    8
#define E_    64
#define M_    64
#define DFF_  2048
#define MARK_ 4
#define KWIN  25
#define PW    12
#define LF    257
#define PRED_ 256
#define EPS_  1e-5f

static __device__ __forceinline__ int iclamp(int v, int lo, int hi) {
  return v < lo ? lo : (v > hi ? hi : v);
}

// ---------------------------------------------------------------- DFT tables
__global__ void k_dft_tables(float* __restrict__ cosF, float* __restrict__ negsinF,
                             float* __restrict__ c512, float* __restrict__ s512) {
  int i = blockIdx.x * 256 + threadIdx.x;
  if (i < 512) {
    float th = (float)i * (6.283185307179586f / 512.0f);
    c512[i] = cosf(th);
    s512[i] = sinf(th);
  }
  if (i >= 512 * LF) return;
  int t = i / LF, f = i % LF;
  int r = (t * f) & 511;                     // exact phase reduction
  float th = (float)r * (6.283185307179586f / 512.0f);
  cosF[i] = cosf(th);
  negsinF[i] = -sinf(th);
}

// ------------------------------------------- x_enc stats: low_init/high_init
__global__ void k_enc_decomp(const float* __restrict__ x,
                             float* __restrict__ lowi, float* __restrict__ highi) {
  int b = blockIdx.x, c = threadIdx.x;
  if (c >= CIN_) return;
  const float* xb = x + (long)b * LQ * CIN_ + c;
  float s = 0.f;
  for (int t = 0; t < LQ; t++) s += xb[(long)t * CIN_];
  float mean = s / (float)LQ;
  for (int t = 256; t < LQ; t++) {
    float w = 0.f;
    for (int j = t - PW; j <= t + PW; j++) {
      int jj = iclamp(j, 0, LQ - 1);
      w += xb[(long)jj * CIN_];
    }
    float m = w * (1.f / KWIN);
    lowi [((long)b * LQ + (t - 256)) * CIN_ + c] = m;
    highi[((long)b * LQ + (t - 256)) * CIN_ + c] = xb[(long)t * CIN_] - m;
  }
  for (int t = 256; t < LQ; t++) {
    lowi [((long)b * LQ + t) * CIN_ + c] = mean;
    highi[((long)b * LQ + t) * CIN_ + c] = 0.f;
  }
}

// ----------------------------------------------------------------- embedding
__global__ void k_embed(const float* __restrict__ x, const float* __restrict__ mark,
                        const float* __restrict__ ck, const float* __restrict__ tw,
                        float* __restrict__ out) {
  int o = blockIdx.x * 256 + threadIdx.x;   // < D
  int t = blockIdx.y, b = blockIdx.z;
  float acc = 0.f;
  const float* xb = x + (long)b * LQ * CIN_;
  #pragma unroll
  for (int j = 0; j < 3; j++) {
    int tt = (t + j - 1 + LQ) & (LQ - 1);
    const float* xr = xb + (long)tt * CIN_;
    const float* kr = ck + (long)(j * CIN_) * D_ + o;
    for (int c = 0; c < CIN_; c++) acc = fmaf(xr[c], kr[(long)c * D_], acc);
  }
  const float* mr = mark + ((long)b * LQ + t) * MARK_;
  #pragma unroll
  for (int mm = 0; mm < MARK_; mm++) acc = fmaf(mr[mm], tw[(long)mm * D_ + o], acc);
  out[((long)b * LQ + t) * D_ + o] = acc;
}

// ------------------------------------------------------------------ fp32 GEMM
// C = act(A * Bm + bias). REQUIRES: Mr%128==0, Nd%128==0, Kd%32==0.
// 128x128 block tile, 256 threads, 8x8 micro-tile.
// As is k-major [32][129]: write pattern (4k4+c+row)%32 is <=2-way (free);
// frag reads are 4-address broadcasts. Bs row-major [32][128], float4 I/O.
template<int ACT>
__global__ __launch_bounds__(256) void k_gemm(
    const float* __restrict__ A, const float* __restrict__ Bm,
    const float* __restrict__ bias, float* __restrict__ C,
    int Mr, int Nd, int Kd) {
  constexpr int BM = 128, BN = 128, BK = 32, SA = BM + 1;
  __shared__ float As[BK][SA];
  __shared__ float Bs[BK][BN];
  int m0 = blockIdx.y * BM, n0 = blockIdx.x * BN;
  int tid = threadIdx.x;
  int tx = tid & 15, ty = tid >> 4;
  float acc[8][8] = {};
  const float* Ag = A + (long)m0 * Kd;
  for (int k0 = 0; k0 < Kd; k0 += BK) {
    #pragma unroll
    for (int r = 0; r < 4; r++) {
      int slot = tid + r * 256;
      int row = slot >> 3, k4 = slot & 7;
      const float4 v = *(const float4*)&Ag[(long)row * Kd + k0 + k4 * 4];
      As[k4 * 4 + 0][row] = v.x; As[k4 * 4 + 1][row] = v.y;
      As[k4 * 4 + 2][row] = v.z; As[k4 * 4 + 3][row] = v.w;
    }
    #pragma unroll
    for (int r = 0; r < 4; r++) {
      int slot = tid + r * 256;
      int kk = slot >> 5, n4 = slot & 31;
      *(float4*)&Bs[kk][n4 * 4] = *(const float4*)&Bm[(long)(k0 + kk) * Nd + n0 + n4 * 4];
    }
    __syncthreads();
    #pragma unroll
    for (int kk = 0; kk < BK; kk++) {
      float av[8], bv[8];
      #pragma unroll
      for (int i = 0; i < 8; i++) av[i] = As[kk][ty * 8 + i];
      #pragma unroll
      for (int j = 0; j < 8; j++) bv[j] = Bs[kk][tx * 8 + j];
      #pragma unroll
      for (int i = 0; i < 8; i++)
        #pragma unroll
        for (int j = 0; j < 8; j++)
          acc[i][j] = fmaf(av[i], bv[j], acc[i][j]);
    }
    __syncthreads();
  }
  float bj[8];
  #pragma unroll
  for (int j = 0; j < 8; j++) bj[j] = bias ? bias[n0 + tx * 8 + j] : 0.f;
  #pragma unroll
  for (int i = 0; i < 8; i++) {
    long gm = m0 + ty * 8 + i;
    float* Crow = C + gm * Nd + n0 + tx * 8;
    #pragma unroll
    for (int j4 = 0; j4 < 2; j4++) {
      float4 v;
      float t0[4];
      #pragma unroll
      for (int j = 0; j < 4; j++) {
        float x = acc[i][j4 * 4 + j] + bj[j4 * 4 + j];
        if (ACT == 1) {   // jax.nn.gelu approximate=True
          float x3 = x * x * x;
          float th = tanhf(0.7978845608028654f * (x + 0.044715f * x3));
          x = 0.5f * x * (1.f + th);
        }
        t0[j] = x;
      }
      v.x = t0[0]; v.y = t0[1]; v.z = t0[2]; v.w = t0[3];
      *(float4*)&Crow[j4 * 4] = v;
    }
  }
}

// ----------------------------------------------------------------- utilities
__global__ void k_zero(float* __restrict__ p, int n) {
  int i = blockIdx.x * 256 + threadIdx.x;
  if (i < n) p[i] = 0.f;
}

// --------------- DFT + |.| epilogue -> amp[f] (no spectrum materialization)
// rows r = b*512 + d; xf[r,f] = sum_t X[b,t,d] * e^{-2 pi i f t/512}
__global__ __launch_bounds__(256) void k_specamp(
    const float* __restrict__ X, const float* __restrict__ cosT,
    const float* __restrict__ nsinT, float* __restrict__ amp) {
  int m0 = blockIdx.y * 64, n0 = blockIdx.x * 64;
  int tid = threadIdx.x, tx = tid & 15, ty = tid >> 4;
  __shared__ float As[32][64];
  __shared__ float Cs[32][65];
  __shared__ float Ss[32][65];
  float aR[4][4] = {}, aI[4][4] = {};
  int b = m0 >> 9, d0 = m0 & 511;
  const float* Xb = X + (long)b * LQ * D_ + d0;
  for (int k0 = 0; k0 < 512; k0 += 32) {
    {
      int mm = tid & 63, kk0 = tid >> 6;
      #pragma unroll
      for (int r = 0; r < 8; r++) {
        int kk = kk0 + r * 4;
        As[kk][mm] = Xb[(long)(k0 + kk) * D_ + mm];
      }
    }
    {
      int nn = tid & 63, kk0 = tid >> 6;
      #pragma unroll
      for (int r = 0; r < 8; r++) {
        int kk = kk0 + r * 4;
        int gn = n0 + nn;
        float c = 0.f, s = 0.f;
        if (gn < LF) { long a = (long)(k0 + kk) * LF + gn; c = cosT[a]; s = nsinT[a]; }
        Cs[kk][nn] = c; Ss[kk][nn] = s;
      }
    }
    __syncthreads();
    #pragma unroll
    for (int kk = 0; kk < 32; kk++) {
      float av[4], cv[4], sv[4];
      #pragma unroll
      for (int i = 0; i < 4; i++) av[i] = As[kk][ty * 4 + i];
      #pragma unroll
      for (int j = 0; j < 4; j++) { cv[j] = Cs[kk][tx * 4 + j]; sv[j] = Ss[kk][tx * 4 + j]; }
      #pragma unroll
      for (int i = 0; i < 4; i++)
        #pragma unroll
        for (int j = 0; j < 4; j++) {
          aR[i][j] = fmaf(av[i], cv[j], aR[i][j]);
          aI[i][j] = fmaf(av[i], sv[j], aI[i][j]);
        }
    }
    __syncthreads();
  }
  __shared__ float csum[64];
  if (tid < 64) csum[tid] = 0.f;
  __syncthreads();
  #pragma unroll
  for (int j = 0; j < 4; j++) {
    float s = 0.f;
    #pragma unroll
    for (int i = 0; i < 4; i++) s += sqrtf(aR[i][j] * aR[i][j] + aI[i][j] * aI[i][j]);
    atomicAdd(&csum[tx * 4 + j], s);
  }
  __syncthreads();
  if (tid < 64 && n0 + tid < LF) atomicAdd(&amp[n0 + tid], csum[tid]);
}

// stable descending top-64 of amp[257] (ties -> lower index, like lax.top_k)
__global__ void k_topk(const float* __restrict__ amp, int* __restrict__ idx) {
  __shared__ float v[512];
  __shared__ float rv[512];
  __shared__ int   ri[512];
  int tid = threadIdx.x;          // 512 threads
  v[tid] = (tid < LF) ? amp[tid] : -INFINITY;
  __syncthreads();
  for (int k = 0; k < M_; k++) {
    rv[tid] = v[tid]; ri[tid] = tid;
    __syncthreads();
    for (int st = 256; st > 0; st >>= 1) {
      if (tid < st) {
        float a = rv[tid], b = rv[tid + st];
        int ai = ri[tid], bi = ri[tid + st];
        if (b > a || (b == a && bi < ai)) { rv[tid] = b; ri[tid] = bi; }
      }
      __syncthreads();
    }
    if (tid == 0) { idx[k] = ri[0]; v[ri[0]] = -INFINITY; }
    __syncthreads();
  }
}

// ------------- direct DFT at the 64 selected freqs -> gR/gI [(b*H+h)*E+e][64]
__global__ __launch_bounds__(256) void k_gatherdft(
    const float* __restrict__ X, const float* __restrict__ cosT,
    const float* __restrict__ nsinT, const int* __restrict__ idx,
    float* __restrict__ gR, float* __restrict__ gI) {
  int m0 = blockIdx.x * 64;
  int tid = threadIdx.x, tx = tid & 15, ty = tid >> 4;
  __shared__ float As[32][64];
  __shared__ float Cs[32][65];
  __shared__ float Ss[32][65];
  __shared__ int fsel[64];
  if (tid < 64) fsel[tid] = idx[tid];
  __syncthreads();
  float aR[4][4] = {}, aI[4][4] = {};
  int b = m0 >> 9, d0 = m0 & 511;
  const float* Xb = X + (long)b * LQ * D_ + d0;
  for (int k0 = 0; k0 < 512; k0 += 32) {
    {
      int mm = tid & 63, kk0 = tid >> 6;
      #pragma unroll
      for (int r = 0; r < 8; r++) {
        int kk = kk0 + r * 4;
        As[kk][mm] = Xb[(long)(k0 + kk) * D_ + mm];
      }
    }
    {
      int nn = tid & 63, kk0 = tid >> 6;
      int f = fsel[nn];
      #pragma unroll
      for (int r = 0; r < 8; r++) {
        int kk = kk0 + r * 4;
        long a = (long)(k0 + kk) * LF + f;
        Cs[kk][nn] = cosT[a]; Ss[kk][nn] = nsinT[a];
      }
    }
    __syncthreads();
    #pragma unroll
    for (int kk = 0; kk < 32; kk++) {
      float av[4], cv[4], sv[4];
      #pragma unroll
      for (int i = 0; i < 4; i++) av[i] = As[kk][ty * 4 + i];
      #pragma unroll
      for (int j = 0; j < 4; j++) { cv[j] = Cs[kk][tx * 4 + j]; sv[j] = Ss[kk][tx * 4 + j]; }
      #pragma unroll
      for (int i = 0; i < 4; i++)
        #pragma unroll
        for (int j = 0; j < 4; j++) {
          aR[i][j] = fmaf(av[i], cv[j], aR[i][j]);
          aI[i][j] = fmaf(av[i], sv[j], aI[i][j]);
        }
    }
    __syncthreads();
  }
  #pragma unroll
  for (int i = 0; i < 4; i++) {
    long row = m0 + ty * 4 + i;
    #pragma unroll
    for (int j = 0; j < 4; j++) {
      gR[row * 64 + tx * 4 + j] = aR[i][j];
      gI[row * 64 + tx * 4 + j] = aI[i][j];
    }
  }
}

// ------------------- outs[b,h,o,m] = sum_e src[b,h,e,m] * w[h,e,o,m] (complex)
__global__ __launch_bounds__(256) void k_modemix(
    const float* __restrict__ sre, const float* __restrict__ sim,
    const float* __restrict__ wre, const float* __restrict__ wim,
    float* __restrict__ ore, float* __restrict__ oim) {
  int b = blockIdx.z, h = blockIdx.y, oc = blockIdx.x;
  int m = threadIdx.x, osub = threadIdx.y;
  int o = oc * 4 + osub;
  __shared__ float xr[E_][M_], xi[E_][M_];
  #pragma unroll
  for (int r = 0; r < 16; r++) {
    int e = r * 4 + osub;
    long a = ((long)(b * H_ + h) * E_ + e) * M_ + m;
    xr[e][m] = sre[a]; xi[e][m] = sim[a];
  }
  __syncthreads();
  float ar = 0.f, ai = 0.f;
  const float* wrb = wre + ((long)(h * E_) * E_ + o) * M_ + m;
  const float* wib = wim + ((long)(h * E_) * E_ + o) * M_ + m;
  #pragma unroll 4
  for (int e = 0; e < E_; e++) {
    float wr = wrb[(long)e * E_ * M_], wi = wib[(long)e * E_ * M_];
    float qr = xr[e][m], qi = xi[e][m];
    ar = fmaf(qr, wr, ar); ar = fmaf(-qi, wi, ar);
    ai = fmaf(qr, wi, ai); ai = fmaf(qi, wr, ai);
  }
  long oaddr = ((long)(b * H_ + h) * E_ + o) * M_ + m;
  ore[oaddr] = ar; oim[oaddr] = ai;
}

// --------------- sparse irfft of 64 modes, writes [B,L,D] layout (d = h*E+o)
__global__ __launch_bounds__(512) void k_irfft(
    const float* __restrict__ ore, const float* __restrict__ oim,
    const int* __restrict__ idx, const float* __restrict__ c512,
    const float* __restrict__ s512, float scale, float* __restrict__ out) {
  int d = blockIdx.x, b = blockIdx.y, t = threadIdx.x;
  int h = d >> 6, o = d & 63;
  __shared__ float mr[M_], mi[M_];
  __shared__ int   mf[M_];
  __shared__ float cs[512], sn[512];
  cs[t] = c512[t]; sn[t] = s512[t];
  if (t < M_) {
    long a = ((long)(b * H_ + h) * E_ + o) * M_ + t;
    int f = idx[t];
    mf[t] = f;
    float c = (f == 0 || f == 256) ? 1.f : 2.f;   // DC / Nyquist: no doubling
    mr[t] = ore[a] * c; mi[t] = oim[a] * c;
  }
  __syncthreads();
  float acc = 0.f;
  #pragma unroll 8
  for (int m = 0; m < M_; m++) {
    int r = (mf[m] * t) & 511;
    acc += mr[m] * cs[r] - mi[m] * sn[r];   // Re(X * e^{+i th})
  }
  out[((long)b * LQ + t) * D_ + d] = acc * scale;
}

// ---------------------------------------- series_decomp (direct 25-window)
// s = a (+ bsrc); season = s - movmean(s); trend: 0 none, 1 write, 2 accumulate
__global__ void k_decomp(const float* __restrict__ a, const float* __restrict__ bsrc,
                         float* __restrict__ season, float* __restrict__ trend,
                         int trendMode) {
  int c = blockIdx.x * 256 + threadIdx.x;
  int t = blockIdx.y, b = blockIdx.z;
  long base = (long)b * LQ * D_ + c;
  float s = 0.f;
  #pragma unroll
  for (int j = -PW; j <= PW; j++) {
    int tt = iclamp(t + j, 0, LQ - 1);
    float v = a[base + (long)tt * D_];
    if (bsrc) v += bsrc[base + (long)tt * D_];
    s += v;
  }
  float m = s * (1.f / KWIN);
  float cur = a[base + (long)t * D_];
  if (bsrc) cur += bsrc[base + (long)t * D_];
  season[base + (long)t * D_] = cur - m;
  if (trendMode == 1) trend[base + (long)t * D_] = m;
  else if (trendMode == 2) trend[base + (long)t * D_] += m;
}

// ------------------------------------------------------------- layernorm ops
__global__ __launch_bounds__(256) void k_ln(const float* __restrict__ x,
                                            const float* __restrict__ g,
                                            const float* __restrict__ bt,
                                            float* __restrict__ out) {
  long row = blockIdx.x;
  const float* xr = x + row * D_;
  float v1 = xr[threadIdx.x], v2 = xr[threadIdx.x + 256];
  __shared__ float rs[256], rq[256];
  rs[threadIdx.x] = v1 + v2;
  rq[threadIdx.x] = v1 * v1 + v2 * v2;
  __syncthreads();
  for (int st = 128; st > 0; st >>= 1) {
    if (threadIdx.x < st) { rs[threadIdx.x] += rs[threadIdx.x + st]; rq[threadIdx.x] += rq[threadIdx.x + st]; }
    __syncthreads();
  }
  float mu = rs[0] / (float)D_;
  float var = fmaxf(rq[0] / (float)D_ - mu * mu, 0.f);
  float inv = rsqrtf(var + EPS_);
  out[row * D_ + threadIdx.x]       = (v1 - mu) * inv * g[threadIdx.x]       + bt[threadIdx.x];
  out[row * D_ + threadIdx.x + 256] = (v2 - mu) * inv * g[threadIdx.x + 256] + bt[threadIdx.x + 256];
}

__global__ void k_tmsub(const float* __restrict__ x, float* __restrict__ out) {
  int dcol = blockIdx.x * 256 + threadIdx.x, b = blockIdx.y;
  long base = (long)b * LQ * D_ + dcol;
  float s = 0.f;
  for (int t = 0; t < LQ; t++) s += x[base + (long)t * D_];
  float mu = s / (float)LQ;
  for (int t = 0; t < LQ; t++) out[base + (long)t * D_] = x[base + (long)t * D_] - mu;
}

// ---------------------------------------- cross attn: qk = ctanh(qs . ks)
// inputs gathered: q/k [(b*H+h)*E+e][64]
__global__ __launch_bounds__(256) void k_qk(
    const float* __restrict__ qR, const float* __restrict__ qI,
    const float* __restrict__ kR, const float* __restrict__ kI,
    float* __restrict__ qkre, float* __restrict__ qkim) {  // [b,h,y,x]
  int b = blockIdx.z, h = blockIdx.y, xc = blockIdx.x;
  int y = threadIdx.x, xs4 = threadIdx.y;
  __shared__ float ksr[E_][64], ksi[E_][64];
  __shared__ float qsr[E_][16], qsi[E_][16];
  long base = (long)(b * H_ + h) * E_;
  int tid = threadIdx.y * 64 + threadIdx.x;
  #pragma unroll
  for (int r = 0; r < 16; r++) {
    int e = r * 4 + xs4;
    long a = (base + e) * 64 + y;
    ksr[e][y] = kR[a]; ksi[e][y] = kI[a];
  }
  #pragma unroll
  for (int r = 0; r < 4; r++) {
    int ii = tid + r * 256;
    int e = ii >> 4, xl = ii & 15;
    long a = (base + e) * 64 + xc * 16 + xl;
    qsr[e][xl] = qR[a]; qsi[e][xl] = qI[a];
  }
  __syncthreads();
  #pragma unroll
  for (int xi = 0; xi < 4; xi++) {
    int xl = xs4 * 4 + xi;
    float ar = 0.f, ai = 0.f;
    for (int e = 0; e < E_; e++) {
      float a1 = qsr[e][xl], b1 = qsi[e][xl], c1 = ksr[e][y], d1 = ksi[e][y];
      ar += a1 * c1 - b1 * d1;
      ai += a1 * d1 + b1 * c1;
    }
    float s = tanhf(ar), t = tanf(ai);
    float t2 = t * t;
    float den = 1.f + s * s * t2;
    float outr = s * (1.f + t2) / den;
    float outi = t * (1.f - s * s) / den;
    int x = xc * 16 + xl;
    long oa = ((long)(b * H_ + h) * M_ + y) * M_ + x;
    qkre[oa] = outr; qkim[oa] = outi;
  }
}

// qkv[b,h,e,x] = sum_y qk[b,h,x,y] * ks[b,h,e,y]  (ks gathered)
__global__ __launch_bounds__(256) void k_qkv(
    const float* __restrict__ qkre, const float* __restrict__ qkim,   // [b,h,y,x]
    const float* __restrict__ kR, const float* __restrict__ kI,
    float* __restrict__ vre, float* __restrict__ vim) {               // [b,h,e,x]
  int b = blockIdx.z, h = blockIdx.y, ec = blockIdx.x;
  int x = threadIdx.x, es = threadIdx.y;
  int e = ec * 4 + es;
  __shared__ float qr[M_][M_], qi2[M_][M_];
  int tid = threadIdx.y * 64 + threadIdx.x;
  #pragma unroll
  for (int r = 0; r < 16; r++) {
    int ii = tid + r * 256;
    int yy = ii >> 6, xx = ii & 63;
    long a = ((long)(b * H_ + h) * M_ + yy) * M_ + xx;
    qr[yy][xx] = qkre[a]; qi2[yy][xx] = qkim[a];
  }
  __syncthreads();
  float ar = 0.f, ai = 0.f;
  long kbase = ((long)(b * H_ + h) * E_ + e) * 64;
  for (int y = 0; y < M_; y++) {
    float c1 = kR[kbase + y], d1 = kI[kbase + y];
    float a1 = qr[y][x], b1 = qi2[y][x];
    ar += a1 * c1 - b1 * d1;
    ai += a1 * d1 + b1 * c1;
  }
  long o = ((long)(b * H_ + h) * E_ + e) * M_ + x;
  vre[o] = ar; vim[o] = ai;
}

// ---------------------------------------------------------------- final fuse
__global__ __launch_bounds__(256) void k_final(
    const float* __restrict__ lowi, const float* __restrict__ tsum,
    const float* __restrict__ tp, const float* __restrict__ ln3,
    const float* __restrict__ projW, const float* __restrict__ projb,
    float* __restrict__ out) {
  int o = threadIdx.x;                         // 0..31 (21 active)
  int rowi = blockIdx.x * 8 + threadIdx.y;     // 0..8191
  int b = rowi >> 8, tpi = rowi & 255;
  int t = tpi + 256;
  if (o >= COUT_) return;
  float acc = lowi[((long)b * LQ + t) * CIN_ + o] + projb[o];
  #pragma unroll
  for (int j = 0; j < 3; j++) {
    int tt = (t + j - 1 + LQ) & (LQ - 1);
    const float* xr = tsum + ((long)b * LQ + tt) * D_;
    const float* kr = tp + (long)(j * D_) * COUT_ + o;
    for (int c = 0; c < D_; c++) acc = fmaf(xr[c], kr[(long)c * COUT_], acc);
  }
  const float* lr = ln3 + ((long)b * LQ + t) * D_;
  for (int d0 = 0; d0 < D_; d0++) acc = fmaf(lr[d0], projW[(long)d0 * COUT_ + o], acc);
  out[((long)b * PRED_ + tpi) * COUT_ + o] = acc;
}

// ============================================================================
extern "C" void kernel_launch(void* const* d_in, const int* in_sizes, int n_in,
                              void* d_out, int out_size, void* d_ws, size_t ws_size,
                              hipStream_t stream) {
  const float* x_enc      = (const float*)d_in[0];
  const float* x_mark_enc = (const float*)d_in[1];
  const float* x_mark_dec = (const float*)d_in[3];
  const float* emb_enc_k  = (const float*)d_in[4];
  const float* emb_enc_t  = (const float*)d_in[5];
  const float* emb_dec_k  = (const float*)d_in[6];
  const float* emb_dec_t  = (const float*)d_in[7];
  const float* fw_enc_re  = (const float*)d_in[8];
  const float* fw_enc_im  = (const float*)d_in[9];
  const float* fw_dec_re  = (const float*)d_in[10];
  const float* fw_dec_im  = (const float*)d_in[11];
  const float* fw_cr_re   = (const float*)d_in[12];
  const float* fw_cr_im   = (const float*)d_in[13];
  const float* enc_Wq     = (const float*)d_in[14];
  const float* enc_bq     = (const float*)d_in[15];
  const float* enc_Wo     = (const float*)d_in[16];
  const float* enc_bo     = (const float*)d_in[17];
  const float* enc_c1     = (const float*)d_in[18];
  const float* enc_c2     = (const float*)d_in[19];
  const float* enc_ng     = (const float*)d_in[20];
  const float* enc_nb     = (const float*)d_in[21];
  const float* ds_Wq      = (const float*)d_in[22];
  const float* ds_bq      = (const float*)d_in[23];
  const float* ds_Wo      = (const float*)d_in[24];
  const float* ds_bo      = (const float*)d_in[25];
  const float* dc_Wq      = (const float*)d_in[26];
  const float* dc_bq      = (const float*)d_in[27];
  const float* dc_Wk      = (const float*)d_in[28];
  const float* dc_bk      = (const float*)d_in[29];
  const float* dc_Wo      = (const float*)d_in[30];
  const float* dc_bo      = (const float*)d_in[31];
  const float* dec_c1     = (const float*)d_in[32];
  const float* dec_c2     = (const float*)d_in[33];
  const float* dec_tp     = (const float*)d_in[34];
  const float* dec_ng     = (const float*)d_in[35];
  const float* dec_nb     = (const float*)d_in[36];
  const float* proj_W     = (const float*)d_in[37];
  const float* proj_b     = (const float*)d_in[38];
  float* out = (float*)d_out;
  float* ws  = (float*)d_ws;

  // ---- workspace layout (floats); FF region sized adaptively vs ws_size
  constexpr size_t BIG = (size_t)B_ * LQ * D_;      // 8388608
  constexpr size_t OUS = (size_t)B_ * H_ * E_ * M_; // 1048576
  size_t o = 0;
  auto nxt = [&](size_t n) { size_t r = o; o += (n + 255) & ~(size_t)255; return r; };
  size_t oA = nxt(BIG), oB = nxt(BIG), oC = nxt(BIG), oTS = nxt(BIG);
  size_t oQSR = nxt(OUS), oQSI = nxt(OUS), oKSR = nxt(OUS), oKSI = nxt(OUS),
         oOR = nxt(OUS), oOI = nxt(OUS), oQKR = nxt(OUS), oQKI = nxt(OUS);
  size_t oCOS = nxt((size_t)512 * LF), oNSN = nxt((size_t)512 * LF);
  size_t oC5 = nxt(512), oS5 = nxt(512);
  size_t oAMP = nxt(512), oIQ = nxt(64), oIK = nxt(64);
  size_t oLOW = nxt((size_t)B_ * LQ * CIN_), oHI = nxt((size_t)B_ * LQ * CIN_);
  size_t oFF = nxt(0);
  // adaptive FFN row-chunk: biggest intermediate that fits the workspace
  int FCH = 2048;
  if ((oFF + (size_t)16384 * DFF_) * 4 <= ws_size)      FCH = 16384;
  else if ((oFF + (size_t)4096 * DFF_) * 4 <= ws_size)  FCH = 4096;
  (void)in_sizes; (void)n_in; (void)out_size;

  int* idxq = (int*)(ws + oIQ);
  int* idxk = (int*)(ws + oIK);

  auto GEMM = [&](const float* Ap, const float* Bp, const float* bias,
                  float* Cp, int Mr, int Nd, int Kd, int act) {
    dim3 g(Nd / 128, Mr / 128, 1);
    if (act) k_gemm<1><<<g, dim3(256), 0, stream>>>(Ap, Bp, bias, Cp, Mr, Nd, Kd);
    else     k_gemm<0><<<g, dim3(256), 0, stream>>>(Ap, Bp, bias, Cp, Mr, Nd, Kd);
  };
  auto AMPSEL = [&](const float* x, int* idxp) {
    k_zero<<<2, 256, 0, stream>>>(ws + oAMP, 512);
    k_specamp<<<dim3(5, 256), 256, 0, stream>>>(x, ws + oCOS, ws + oNSN, ws + oAMP);
    k_topk<<<1, 512, 0, stream>>>(ws + oAMP, idxp);
  };
  auto GATHER = [&](const float* x, const int* idxp, float* gR, float* gI) {
    k_gatherdft<<<256, 256, 0, stream>>>(x, ws + oCOS, ws + oNSN, idxp, gR, gI);
  };
  auto MODEMIX = [&](const float* sR, const float* sI, const float* wre, const float* wim) {
    k_modemix<<<dim3(16, H_, B_), dim3(64, 4), 0, stream>>>(sR, sI, wre, wim, ws + oOR, ws + oOI);
  };
  auto IRFFT = [&](const int* idxp, float scale, float* dst) {
    k_irfft<<<dim3(D_, B_), 512, 0, stream>>>(ws + oOR, ws + oOI, idxp,
                                              ws + oC5, ws + oS5, scale, dst);
  };
  auto DECOMP = [&](const float* a, const float* bsrc, float* season, float* trend, int mode) {
    k_decomp<<<dim3(2, LQ, B_), 256, 0, stream>>>(a, bsrc, season, trend, mode);
  };
  auto FFNP = [&](const float* x, const float* c1, const float* c2, float* y) {
    for (int ch = 0; ch < (B_ * LQ) / FCH; ch++) {
      GEMM(x + (size_t)ch * FCH * D_, c1, nullptr, ws + oFF, FCH, DFF_, D_, 1);
      GEMM(ws + oFF, c2, nullptr, y + (size_t)ch * FCH * D_, FCH, D_, DFF_, 0);
    }
  };

  // ---- prologue
  k_dft_tables<<<(512 * LF + 255) / 256, 256, 0, stream>>>(ws + oCOS, ws + oNSN,
                                                           ws + oC5, ws + oS5);
  k_enc_decomp<<<B_, 32, 0, stream>>>(x_enc, ws + oLOW, ws + oHI);
  k_embed<<<dim3(2, LQ, B_), 256, 0, stream>>>(x_enc, x_mark_enc, emb_enc_k, emb_enc_t, ws + oA);

  // ---- encoder (enc lives in A; temporaries B, C)
  for (int i = 0; i < 2; i++) {
    GEMM(ws + oA, enc_Wq + (size_t)i * D_ * D_, enc_bq + (size_t)i * D_, ws + oB, B_ * LQ, D_, D_, 0);
    AMPSEL(ws + oB, idxq);
    GATHER(ws + oB, idxq, ws + oQSR, ws + oQSI);
    MODEMIX(ws + oQSR, ws + oQSI, fw_enc_re, fw_enc_im);
    IRFFT(idxq, 1.f / 512.f, ws + oB);
    GEMM(ws + oB, enc_Wo + (size_t)i * D_ * D_, enc_bo + (size_t)i * D_, ws + oC, B_ * LQ, D_, D_, 0);
    DECOMP(ws + oA, ws + oC, ws + oB, nullptr, 0);                       // x1 -> B
    FFNP(ws + oB, enc_c1 + (size_t)i * D_ * DFF_, enc_c2 + (size_t)i * DFF_ * D_, ws + oC);
    DECOMP(ws + oB, ws + oC, ws + oA, nullptr, 0);                       // enc -> A
  }
  k_ln<<<B_ * LQ, 256, 0, stream>>>(ws + oA, enc_ng, enc_nb, ws + oB);
  k_tmsub<<<dim3(2, B_), 256, 0, stream>>>(ws + oB, ws + oA);            // enc final -> A

  // ---- cross-K path (uses final enc, then enc buffer is free)
  GEMM(ws + oA, dc_Wk, dc_bk, ws + oB, B_ * LQ, D_, D_, 0);
  AMPSEL(ws + oB, idxk);
  GATHER(ws + oB, idxk, ws + oKSR, ws + oKSI);

  // ---- decoder (dec -> A)
  k_embed<<<dim3(2, LQ, B_), 256, 0, stream>>>(ws + oHI, x_mark_dec, emb_dec_k, emb_dec_t, ws + oA);
  GEMM(ws + oA, ds_Wq, ds_bq, ws + oB, B_ * LQ, D_, D_, 0);
  AMPSEL(ws + oB, idxq);
  GATHER(ws + oB, idxq, ws + oQSR, ws + oQSI);
  MODEMIX(ws + oQSR, ws + oQSI, fw_dec_re, fw_dec_im);
  IRFFT(idxq, 1.f / 512.f, ws + oB);
  GEMM(ws + oB, ds_Wo, ds_bo, ws + oC, B_ * LQ, D_, D_, 0);              // a -> C
  DECOMP(ws + oA, ws + oC, ws + oB, ws + oTS, 1);                        // x1 -> B, t1 -> TS

  GEMM(ws + oB, dc_Wq, dc_bq, ws + oC, B_ * LQ, D_, D_, 0);              // q -> C
  AMPSEL(ws + oC, idxq);
  GATHER(ws + oC, idxq, ws + oQSR, ws + oQSI);
  k_qk<<<dim3(4, H_, B_), dim3(64, 4), 0, stream>>>(
      ws + oQSR, ws + oQSI, ws + oKSR, ws + oKSI, ws + oQKR, ws + oQKI);
  k_qkv<<<dim3(16, H_, B_), dim3(64, 4), 0, stream>>>(
      ws + oQKR, ws + oQKI, ws + oKSR, ws + oKSI, ws + oQSR, ws + oQSI); // v -> qs bufs
  MODEMIX(ws + oQSR, ws + oQSI, fw_cr_re, fw_cr_im);
  IRFFT(idxq, 1.f / (512.f * 262144.f), ws + oC);
  GEMM(ws + oC, dc_Wo, dc_bo, ws + oA, B_ * LQ, D_, D_, 0);              // c -> A
  DECOMP(ws + oB, ws + oA, ws + oC, ws + oTS, 2);                        // x2 -> C, t2 +=
  FFNP(ws + oC, dec_c1, dec_c2, ws + oA);                                // y -> A
  DECOMP(ws + oC, ws + oA, ws + oB, ws + oTS, 2);                        // x3 -> B, t3 +=
  k_ln<<<B_ * LQ, 256, 0, stream>>>(ws + oB, dec_ng, dec_nb, ws + oA);
  k_tmsub<<<dim3(2, B_), 256, 0, stream>>>(ws + oA, ws + oC);            // ln3 -> C
  k_final<<<dim3(B_ * PRED_ / 8), dim3(32, 8), 0, stream>>>(
      ws + oLOW, ws + oTS, dec_tp, ws + oC, proj_W, proj_b, out);
}

// Round 5
// 9075.027 us; speedup vs baseline: 1.7727x; 1.1066x over previous
//
#include <hip/hip_runtime.h>
#include <math.h>

#define B_    32
#define LQ    512
#define CIN_  21
#define COUT_ 21
#define D_    512
#define H_    8
#define E_    64
#define M_    64
#define DFF_  2048
#define MARK_ 4
#define KWIN  25
#define PW    12
#define LF    257
#define TW    320                 // padded DFT table width (zeros past 257)
#define PRED_ 256
#define EPS_  1e-5f
#define SPECH (16384 * 256)       // spectrum floats per component (rows x 256)

static __device__ __forceinline__ int iclamp(int v, int lo, int hi) {
  return v < lo ? lo : (v > hi ? hi : v);
}

// ---------------------------------------------------------------- DFT tables
__global__ void k_dft_tables(float* __restrict__ cosF, float* __restrict__ negsinF,
                             float* __restrict__ c512, float* __restrict__ s512) {
  int i = blockIdx.x * 256 + threadIdx.x;
  if (i < 512) {
    float th = (float)i * (6.283185307179586f / 512.0f);
    c512[i] = cosf(th);
    s512[i] = sinf(th);
  }
  if (i >= 512 * TW) return;
  int t = i / TW, f = i % TW;
  if (f >= LF) { cosF[i] = 0.f; negsinF[i] = 0.f; return; }
  int r = (t * f) & 511;                     // exact phase reduction
  float th = (float)r * (6.283185307179586f / 512.0f);
  cosF[i] = cosf(th);
  negsinF[i] = -sinf(th);
}

// ------------------------------------------- x_enc stats: low_init/high_init
__global__ void k_enc_decomp(const float* __restrict__ x,
                             float* __restrict__ lowi, float* __restrict__ highi) {
  int b = blockIdx.x, c = threadIdx.x;
  if (c >= CIN_) return;
  const float* xb = x + (long)b * LQ * CIN_ + c;
  float s = 0.f;
  for (int t = 0; t < LQ; t++) s += xb[(long)t * CIN_];
  float mean = s / (float)LQ;
  for (int t = 256; t < LQ; t++) {
    float w = 0.f;
    for (int j = t - PW; j <= t + PW; j++) {
      int jj = iclamp(j, 0, LQ - 1);
      w += xb[(long)jj * CIN_];
    }
    float m = w * (1.f / KWIN);
    lowi [((long)b * LQ + (t - 256)) * CIN_ + c] = m;
    highi[((long)b * LQ + (t - 256)) * CIN_ + c] = xb[(long)t * CIN_] - m;
  }
  for (int t = 256; t < LQ; t++) {
    lowi [((long)b * LQ + t) * CIN_ + c] = mean;
    highi[((long)b * LQ + t) * CIN_ + c] = 0.f;
  }
}

// ----------------------------------------------------------------- embedding
__global__ void k_embed(const float* __restrict__ x, const float* __restrict__ mark,
                        const float* __restrict__ ck, const float* __restrict__ tw,
                        float* __restrict__ out) {
  int o = blockIdx.x * 256 + threadIdx.x;   // < D
  int t = blockIdx.y, b = blockIdx.z;
  float acc = 0.f;
  const float* xb = x + (long)b * LQ * CIN_;
  #pragma unroll
  for (int j = 0; j < 3; j++) {
    int tt = (t + j - 1 + LQ) & (LQ - 1);
    const float* xr = xb + (long)tt * CIN_;
    const float* kr = ck + (long)(j * CIN_) * D_ + o;
    for (int c = 0; c < CIN_; c++) acc = fmaf(xr[c], kr[(long)c * D_], acc);
  }
  const float* mr = mark + ((long)b * LQ + t) * MARK_;
  #pragma unroll
  for (int mm = 0; mm < MARK_; mm++) acc = fmaf(mr[mm], tw[(long)mm * D_ + o], acc);
  out[((long)b * LQ + t) * D_ + o] = acc;
}

// ------------------------------------------------------------------ fp32 GEMM
// C = act(A * Bm + bias). REQUIRES: Mr%128==0, Nd%128==0, Kd%32==0.
template<int ACT>
__global__ __launch_bounds__(256) void k_gemm(
    const float* __restrict__ A, const float* __restrict__ Bm,
    const float* __restrict__ bias, float* __restrict__ C,
    int Mr, int Nd, int Kd) {
  constexpr int BM = 128, BN = 128, BK = 32, SA = BM + 1;
  __shared__ float As[BK][SA];
  __shared__ float Bs[BK][BN];
  int m0 = blockIdx.y * BM, n0 = blockIdx.x * BN;
  int tid = threadIdx.x;
  int tx = tid & 15, ty = tid >> 4;
  float acc[8][8] = {};
  const float* Ag = A + (long)m0 * Kd;
  for (int k0 = 0; k0 < Kd; k0 += BK) {
    #pragma unroll
    for (int r = 0; r < 4; r++) {
      int slot = tid + r * 256;
      int row = slot >> 3, k4 = slot & 7;
      const float4 v = *(const float4*)&Ag[(long)row * Kd + k0 + k4 * 4];
      As[k4 * 4 + 0][row] = v.x; As[k4 * 4 + 1][row] = v.y;
      As[k4 * 4 + 2][row] = v.z; As[k4 * 4 + 3][row] = v.w;
    }
    #pragma unroll
    for (int r = 0; r < 4; r++) {
      int slot = tid + r * 256;
      int kk = slot >> 5, n4 = slot & 31;
      *(float4*)&Bs[kk][n4 * 4] = *(const float4*)&Bm[(long)(k0 + kk) * Nd + n0 + n4 * 4];
    }
    __syncthreads();
    #pragma unroll
    for (int kk = 0; kk < BK; kk++) {
      float av[8], bv[8];
      #pragma unroll
      for (int i = 0; i < 8; i++) av[i] = As[kk][ty * 8 + i];
      #pragma unroll
      for (int j = 0; j < 8; j++) bv[j] = Bs[kk][tx * 8 + j];
      #pragma unroll
      for (int i = 0; i < 8; i++)
        #pragma unroll
        for (int j = 0; j < 8; j++)
          acc[i][j] = fmaf(av[i], bv[j], acc[i][j]);
    }
    __syncthreads();
  }
  float bj[8];
  #pragma unroll
  for (int j = 0; j < 8; j++) bj[j] = bias ? bias[n0 + tx * 8 + j] : 0.f;
  #pragma unroll
  for (int i = 0; i < 8; i++) {
    long gm = m0 + ty * 8 + i;
    float* Crow = C + gm * Nd + n0 + tx * 8;
    #pragma unroll
    for (int j4 = 0; j4 < 2; j4++) {
      float4 v;
      float t0[4];
      #pragma unroll
      for (int j = 0; j < 4; j++) {
        float x = acc[i][j4 * 4 + j] + bj[j4 * 4 + j];
        if (ACT == 1) {   // jax.nn.gelu approximate=True
          float x3 = x * x * x;
          float th = tanhf(0.7978845608028654f * (x + 0.044715f * x3));
          x = 0.5f * x * (1.f + th);
        }
        t0[j] = x;
      }
      v.x = t0[0]; v.y = t0[1]; v.z = t0[2]; v.w = t0[3];
      *(float4*)&Crow[j4 * 4] = v;
    }
  }
}

// ----------------------------------------------------------------- utilities
__global__ void k_zero(float* __restrict__ p, int n) {
  int i = blockIdx.x * 256 + threadIdx.x;
  if (i < n) p[i] = 0.f;
}

// ------------- DFT over all 257 freqs: stores spectrum + accumulates amp.
// rows r = b*512 + d; xf[r,f] = sum_t X[b,t,d] e^{-2pi i f t/512}
// specR/specI: [16384][256] (f=0..255); f=256 (Nyquist) in nyqR/nyqI[16384].
// grid (128 row-tiles, 5 freq-tiles), 256 thr, 8x4x2 acc/thread.
__global__ __launch_bounds__(256) void k_dftamp(
    const float* __restrict__ X, const float* __restrict__ cosP,
    const float* __restrict__ nsinP, float* __restrict__ specR,
    float* __restrict__ specI, float* __restrict__ nyqR,
    float* __restrict__ nyqI, float* __restrict__ amp) {
  constexpr int BK = 32;
  __shared__ float As[BK][132];
  __shared__ float Cs[BK][68];
  __shared__ float Ss[BK][68];
  int m0 = blockIdx.x * 128;
  int n0 = blockIdx.y * 64;
  int tid = threadIdx.x, tx = tid & 15, ty = tid >> 4;
  int b = m0 >> 9, d0 = m0 & 511;
  const float* Xb = X + (long)b * LQ * D_ + d0;
  float aR[8][4] = {}, aI[8][4] = {};
  for (int k0 = 0; k0 < 512; k0 += BK) {
    #pragma unroll
    for (int r = 0; r < 4; r++) {
      int slot = tid + r * 256;
      int kk = slot >> 5, d4 = slot & 31;
      *(float4*)&As[kk][d4 * 4] = *(const float4*)&Xb[(long)(k0 + kk) * D_ + d4 * 4];
    }
    #pragma unroll
    for (int r = 0; r < 2; r++) {
      int slot = tid + r * 256;
      int kk = slot >> 4, f4 = slot & 15;
      *(float4*)&Cs[kk][f4 * 4] = *(const float4*)&cosP [(long)(k0 + kk) * TW + n0 + f4 * 4];
      *(float4*)&Ss[kk][f4 * 4] = *(const float4*)&nsinP[(long)(k0 + kk) * TW + n0 + f4 * 4];
    }
    __syncthreads();
    #pragma unroll
    for (int kk = 0; kk < BK; kk++) {
      float av[8], cv[4], sv[4];
      *(float4*)&av[0] = *(const float4*)&As[kk][ty * 8];
      *(float4*)&av[4] = *(const float4*)&As[kk][ty * 8 + 4];
      *(float4*)&cv[0] = *(const float4*)&Cs[kk][tx * 4];
      *(float4*)&sv[0] = *(const float4*)&Ss[kk][tx * 4];
      #pragma unroll
      for (int i = 0; i < 8; i++)
        #pragma unroll
        for (int j = 0; j < 4; j++) {
          aR[i][j] = fmaf(av[i], cv[j], aR[i][j]);
          aI[i][j] = fmaf(av[i], sv[j], aI[i][j]);
        }
    }
    __syncthreads();
  }
  int c0 = n0 + tx * 4;
  #pragma unroll
  for (int i = 0; i < 8; i++) {
    long row = m0 + ty * 8 + i;
    if (c0 < 256) {
      *(float4*)&specR[row * 256 + c0] = make_float4(aR[i][0], aR[i][1], aR[i][2], aR[i][3]);
      *(float4*)&specI[row * 256 + c0] = make_float4(aI[i][0], aI[i][1], aI[i][2], aI[i][3]);
    } else if (c0 == 256) {
      nyqR[row] = aR[i][0];
      nyqI[row] = aI[i][0];
    }
  }
  __shared__ float csum[16][68];
  #pragma unroll
  for (int j = 0; j < 4; j++) {
    float s = 0.f;
    #pragma unroll
    for (int i = 0; i < 8; i++)
      s += sqrtf(aR[i][j] * aR[i][j] + aI[i][j] * aI[i][j]);
    csum[ty][tx * 4 + j] = s;
  }
  __syncthreads();
  if (tid < 64) {
    float s = 0.f;
    #pragma unroll
    for (int r = 0; r < 16; r++) s += csum[r][tid];
    if (n0 + tid < LF) atomicAdd(&amp[n0 + tid], s);
  }
}

// stable descending top-64 of amp[257] (ties -> lower index, like lax.top_k)
__global__ void k_topk(const float* __restrict__ amp, int* __restrict__ idx) {
  __shared__ float v[512];
  __shared__ float rv[512];
  __shared__ int   ri[512];
  int tid = threadIdx.x;          // 512 threads
  v[tid] = (tid < LF) ? amp[tid] : -INFINITY;
  __syncthreads();
  for (int k = 0; k < M_; k++) {
    rv[tid] = v[tid]; ri[tid] = tid;
    __syncthreads();
    for (int st = 256; st > 0; st >>= 1) {
      if (tid < st) {
        float a = rv[tid], b = rv[tid + st];
        int ai = ri[tid], bi = ri[tid + st];
        if (b > a || (b == a && bi < ai)) { rv[tid] = b; ri[tid] = bi; }
      }
      __syncthreads();
    }
    if (tid == 0) { idx[k] = ri[0]; v[ri[0]] = -INFINITY; }
    __syncthreads();
  }
}

// ---------------- gather 64 selected columns from stored spectrum
__global__ void k_gathercols(const float* __restrict__ specR, const float* __restrict__ specI,
                             const float* __restrict__ nyqR, const float* __restrict__ nyqI,
                             const int* __restrict__ idx,
                             float* __restrict__ gR, float* __restrict__ gI) {
  int tid = threadIdx.x;
  int m = tid & 63, r = tid >> 6;
  long row = (long)blockIdx.x * 4 + r;
  int f = idx[m];
  long o = row * 64 + m;
  if (f < 256) { gR[o] = specR[row * 256 + f]; gI[o] = specI[row * 256 + f]; }
  else         { gR[o] = nyqR[row];            gI[o] = nyqI[row]; }
}

// ------------------- outs[b,h,o,m] = sum_e src[b,h,e,m] * w[h,e,o,m] (complex)
__global__ __launch_bounds__(256) void k_modemix(
    const float* __restrict__ sre, const float* __restrict__ sim,
    const float* __restrict__ wre, const float* __restrict__ wim,
    float* __restrict__ ore, float* __restrict__ oim) {
  int b = blockIdx.z, h = blockIdx.y, oc = blockIdx.x;
  int m = threadIdx.x, osub = threadIdx.y;
  int o = oc * 4 + osub;
  __shared__ float xr[E_][M_], xi[E_][M_];
  #pragma unroll
  for (int r = 0; r < 16; r++) {
    int e = r * 4 + osub;
    long a = ((long)(b * H_ + h) * E_ + e) * M_ + m;
    xr[e][m] = sre[a]; xi[e][m] = sim[a];
  }
  __syncthreads();
  float ar = 0.f, ai = 0.f;
  const float* wrb = wre + ((long)(h * E_) * E_ + o) * M_ + m;
  const float* wib = wim + ((long)(h * E_) * E_ + o) * M_ + m;
  #pragma unroll 4
  for (int e = 0; e < E_; e++) {
    float wr = wrb[(long)e * E_ * M_], wi = wib[(long)e * E_ * M_];
    float qr = xr[e][m], qi = xi[e][m];
    ar = fmaf(qr, wr, ar); ar = fmaf(-qi, wi, ar);
    ai = fmaf(qr, wi, ai); ai = fmaf(qi, wr, ai);
  }
  long oaddr = ((long)(b * H_ + h) * E_ + o) * M_ + m;
  ore[oaddr] = ar; oim[oaddr] = ai;
}

// --------------- sparse irfft of 64 modes, writes [B,L,D] layout (d = h*E+o)
__global__ __launch_bounds__(512) void k_irfft(
    const float* __restrict__ ore, const float* __restrict__ oim,
    const int* __restrict__ idx, const float* __restrict__ c512,
    const float* __restrict__ s512, float scale, float* __restrict__ out) {
  int d = blockIdx.x, b = blockIdx.y, t = threadIdx.x;
  int h = d >> 6, o = d & 63;
  __shared__ float mr[M_], mi[M_];
  __shared__ int   mf[M_];
  __shared__ float cs[512], sn[512];
  cs[t] = c512[t]; sn[t] = s512[t];
  if (t < M_) {
    long a = ((long)(b * H_ + h) * E_ + o) * M_ + t;
    int f = idx[t];
    mf[t] = f;
    float c = (f == 0 || f == 256) ? 1.f : 2.f;   // DC / Nyquist: no doubling
    mr[t] = ore[a] * c; mi[t] = oim[a] * c;
  }
  __syncthreads();
  float acc = 0.f;
  #pragma unroll 8
  for (int m = 0; m < M_; m++) {
    int r = (mf[m] * t) & 511;
    acc += mr[m] * cs[r] - mi[m] * sn[r];   // Re(X * e^{+i th})
  }
  out[((long)b * LQ + t) * D_ + d] = acc * scale;
}

// ---------------------------------------- series_decomp via sliding window
// s = a (+ bsrc); season = s - movmean(s); trend: 0 none, 1 write, 2 accumulate
// grid (D/256, LQ/64, B); each thread owns a column and a 64-t chunk.
__global__ void k_decomp(const float* __restrict__ a, const float* __restrict__ bsrc,
                         float* __restrict__ season, float* __restrict__ trend,
                         int trendMode) {
  int c = blockIdx.x * 256 + threadIdx.x;
  int t0 = blockIdx.y * 64;
  int b = blockIdx.z;
  long base = (long)b * LQ * D_ + c;
  float s = 0.f;
  for (int j = t0 - PW; j <= t0 + PW; j++) {
    int tt = iclamp(j, 0, LQ - 1);
    float v = a[base + (long)tt * D_];
    if (bsrc) v += bsrc[base + (long)tt * D_];
    s += v;
  }
  for (int t = t0; t < t0 + 64; t++) {
    float cur = a[base + (long)t * D_];
    if (bsrc) cur += bsrc[base + (long)t * D_];
    float m = s * (1.f / KWIN);
    season[base + (long)t * D_] = cur - m;
    if (trendMode == 1) trend[base + (long)t * D_] = m;
    else if (trendMode == 2) trend[base + (long)t * D_] += m;
    int tn = iclamp(t + PW + 1, 0, LQ - 1), to = iclamp(t - PW, 0, LQ - 1);
    float vn = a[base + (long)tn * D_], vo = a[base + (long)to * D_];
    if (bsrc) { vn += bsrc[base + (long)tn * D_]; vo += bsrc[base + (long)to * D_]; }
    s += vn - vo;
  }
}

// ------------------------------------------------------------- layernorm ops
__global__ __launch_bounds__(256) void k_ln(const float* __restrict__ x,
                                            const float* __restrict__ g,
                                            const float* __restrict__ bt,
                                            float* __restrict__ out) {
  long row = blockIdx.x;
  const float* xr = x + row * D_;
  float v1 = xr[threadIdx.x], v2 = xr[threadIdx.x + 256];
  __shared__ float rs[256], rq[256];
  rs[threadIdx.x] = v1 + v2;
  rq[threadIdx.x] = v1 * v1 + v2 * v2;
  __syncthreads();
  for (int st = 128; st > 0; st >>= 1) {
    if (threadIdx.x < st) { rs[threadIdx.x] += rs[threadIdx.x + st]; rq[threadIdx.x] += rq[threadIdx.x + st]; }
    __syncthreads();
  }
  float mu = rs[0] / (float)D_;
  float var = fmaxf(rq[0] / (float)D_ - mu * mu, 0.f);
  float inv = rsqrtf(var + EPS_);
  out[row * D_ + threadIdx.x]       = (v1 - mu) * inv * g[threadIdx.x]       + bt[threadIdx.x];
  out[row * D_ + threadIdx.x + 256] = (v2 - mu) * inv * g[threadIdx.x + 256] + bt[threadIdx.x + 256];
}

__global__ void k_tmsub(const float* __restrict__ x, float* __restrict__ out) {
  int dcol = blockIdx.x * 256 + threadIdx.x, b = blockIdx.y;
  long base = (long)b * LQ * D_ + dcol;
  float s = 0.f;
  for (int t = 0; t < LQ; t++) s += x[base + (long)t * D_];
  float mu = s / (float)LQ;
  for (int t = 0; t < LQ; t++) out[base + (long)t * D_] = x[base + (long)t * D_] - mu;
}

// ---------------------------------------- cross attn: qk = ctanh(qs . ks)
// inputs gathered: q/k [(b*H+h)*E+e][64]
__global__ __launch_bounds__(256) void k_qk(
    const float* __restrict__ qR, const float* __restrict__ qI,
    const float* __restrict__ kR, const float* __restrict__ kI,
    float* __restrict__ qkre, float* __restrict__ qkim) {  // [b,h,y,x]
  int b = blockIdx.z, h = blockIdx.y, xc = blockIdx.x;
  int y = threadIdx.x, xs4 = threadIdx.y;
  __shared__ float ksr[E_][64], ksi[E_][64];
  __shared__ float qsr[E_][16], qsi[E_][16];
  long base = (long)(b * H_ + h) * E_;
  int tid = threadIdx.y * 64 + threadIdx.x;
  #pragma unroll
  for (int r = 0; r < 16; r++) {
    int e = r * 4 + xs4;
    long a = (base + e) * 64 + y;
    ksr[e][y] = kR[a]; ksi[e][y] = kI[a];
  }
  #pragma unroll
  for (int r = 0; r < 4; r++) {
    int ii = tid + r * 256;
    int e = ii >> 4, xl = ii & 15;
    long a = (base + e) * 64 + xc * 16 + xl;
    qsr[e][xl] = qR[a]; qsi[e][xl] = qI[a];
  }
  __syncthreads();
  #pragma unroll
  for (int xi = 0; xi < 4; xi++) {
    int xl = xs4 * 4 + xi;
    float ar = 0.f, ai = 0.f;
    for (int e = 0; e < E_; e++) {
      float a1 = qsr[e][xl], b1 = qsi[e][xl], c1 = ksr[e][y], d1 = ksi[e][y];
      ar += a1 * c1 - b1 * d1;
      ai += a1 * d1 + b1 * c1;
    }
    float s = tanhf(ar), t = tanf(ai);
    float t2 = t * t;
    float den = 1.f + s * s * t2;
    float outr = s * (1.f + t2) / den;
    float outi = t * (1.f - s * s) / den;
    int x = xc * 16 + xl;
    long oa = ((long)(b * H_ + h) * M_ + y) * M_ + x;
    qkre[oa] = outr; qkim[oa] = outi;
  }
}

// qkv[b,h,e,x] = sum_y qk[b,h,x,y] * ks[b,h,e,y]  (ks gathered)
__global__ __launch_bounds__(256) void k_qkv(
    const float* __restrict__ qkre, const float* __restrict__ qkim,   // [b,h,y,x]
    const float* __restrict__ kR, const float* __restrict__ kI,
    float* __restrict__ vre, float* __restrict__ vim) {               // [b,h,e,x]
  int b = blockIdx.z, h = blockIdx.y, ec = blockIdx.x;
  int x = threadIdx.x, es = threadIdx.y;
  int e = ec * 4 + es;
  __shared__ float qr[M_][M_], qi2[M_][M_];
  int tid = threadIdx.y * 64 + threadIdx.x;
  #pragma unroll
  for (int r = 0; r < 16; r++) {
    int ii = tid + r * 256;
    int yy = ii >> 6, xx = ii & 63;
    long a = ((long)(b * H_ + h) * M_ + yy) * M_ + xx;
    qr[yy][xx] = qkre[a]; qi2[yy][xx] = qkim[a];
  }
  __syncthreads();
  float ar = 0.f, ai = 0.f;
  long kbase = ((long)(b * H_ + h) * E_ + e) * 64;
  for (int y = 0; y < M_; y++) {
    float c1 = kR[kbase + y], d1 = kI[kbase + y];
    float a1 = qr[y][x], b1 = qi2[y][x];
    ar += a1 * c1 - b1 * d1;
    ai += a1 * d1 + b1 * c1;
  }
  long o = ((long)(b * H_ + h) * E_ + e) * M_ + x;
  vre[o] = ar; vim[o] = ai;
}

// ---------------------------------------------------------------- final fuse
__global__ __launch_bounds__(256) void k_final(
    const float* __restrict__ lowi, const float* __restrict__ tsum,
    const float* __restrict__ tp, const float* __restrict__ ln3,
    const float* __restrict__ projW, const float* __restrict__ projb,
    float* __restrict__ out) {
  int o = threadIdx.x;                         // 0..31 (21 active)
  int rowi = blockIdx.x * 8 + threadIdx.y;     // 0..8191
  int b = rowi >> 8, tpi = rowi & 255;
  int t = tpi + 256;
  if (o >= COUT_) return;
  float acc = lowi[((long)b * LQ + t) * CIN_ + o] + projb[o];
  #pragma unroll
  for (int j = 0; j < 3; j++) {
    int tt = (t + j - 1 + LQ) & (LQ - 1);
    const float* xr = tsum + ((long)b * LQ + tt) * D_;
    const float* kr = tp + (long)(j * D_) * COUT_ + o;
    for (int c = 0; c < D_; c++) acc = fmaf(xr[c], kr[(long)c * COUT_], acc);
  }
  const float* lr = ln3 + ((long)b * LQ + t) * D_;
  for (int d0 = 0; d0 < D_; d0++) acc = fmaf(lr[d0], projW[(long)d0 * COUT_ + o], acc);
  out[((long)b * PRED_ + tpi) * COUT_ + o] = acc;
}

// ============================================================================
extern "C" void kernel_launch(void* const* d_in, const int* in_sizes, int n_in,
                              void* d_out, int out_size, void* d_ws, size_t ws_size,
                              hipStream_t stream) {
  const float* x_enc      = (const float*)d_in[0];
  const float* x_mark_enc = (const float*)d_in[1];
  const float* x_mark_dec = (const float*)d_in[3];
  const float* emb_enc_k  = (const float*)d_in[4];
  const float* emb_enc_t  = (const float*)d_in[5];
  const float* emb_dec_k  = (const float*)d_in[6];
  const float* emb_dec_t  = (const float*)d_in[7];
  const float* fw_enc_re  = (const float*)d_in[8];
  const float* fw_enc_im  = (const float*)d_in[9];
  const float* fw_dec_re  = (const float*)d_in[10];
  const float* fw_dec_im  = (const float*)d_in[11];
  const float* fw_cr_re   = (const float*)d_in[12];
  const float* fw_cr_im   = (const float*)d_in[13];
  const float* enc_Wq     = (const float*)d_in[14];
  const float* enc_bq     = (const float*)d_in[15];
  const float* enc_Wo     = (const float*)d_in[16];
  const float* enc_bo     = (const float*)d_in[17];
  const float* enc_c1     = (const float*)d_in[18];
  const float* enc_c2     = (const float*)d_in[19];
  const float* enc_ng     = (const float*)d_in[20];
  const float* enc_nb     = (const float*)d_in[21];
  const float* ds_Wq      = (const float*)d_in[22];
  const float* ds_bq      = (const float*)d_in[23];
  const float* ds_Wo      = (const float*)d_in[24];
  const float* ds_bo      = (const float*)d_in[25];
  const float* dc_Wq      = (const float*)d_in[26];
  const float* dc_bq      = (const float*)d_in[27];
  const float* dc_Wk      = (const float*)d_in[28];
  const float* dc_bk      = (const float*)d_in[29];
  const float* dc_Wo      = (const float*)d_in[30];
  const float* dc_bo      = (const float*)d_in[31];
  const float* dec_c1     = (const float*)d_in[32];
  const float* dec_c2     = (const float*)d_in[33];
  const float* dec_tp     = (const float*)d_in[34];
  const float* dec_ng     = (const float*)d_in[35];
  const float* dec_nb     = (const float*)d_in[36];
  const float* proj_W     = (const float*)d_in[37];
  const float* proj_b     = (const float*)d_in[38];
  float* out = (float*)d_out;
  float* ws  = (float*)d_ws;

  // ---- workspace layout (floats); FF region sized adaptively vs ws_size
  constexpr size_t BIG = (size_t)B_ * LQ * D_;      // 8388608
  constexpr size_t OUS = (size_t)B_ * H_ * E_ * M_; // 1048576
  size_t o = 0;
  auto nxt = [&](size_t n) { size_t r = o; o += (n + 255) & ~(size_t)255; return r; };
  size_t oA = nxt(BIG), oB = nxt(BIG), oC = nxt(BIG), oTS = nxt(BIG);
  size_t oQSR = nxt(OUS), oQSI = nxt(OUS), oKSR = nxt(OUS), oKSI = nxt(OUS),
         oOR = nxt(OUS), oOI = nxt(OUS), oQKR = nxt(OUS), oQKI = nxt(OUS);
  size_t oCOS = nxt((size_t)512 * TW), oNSN = nxt((size_t)512 * TW);
  size_t oC5 = nxt(512), oS5 = nxt(512);
  size_t oAMP = nxt(512), oIQ = nxt(64), oIK = nxt(64);
  size_t oNR = nxt(16384), oNI = nxt(16384);
  size_t oLOW = nxt((size_t)B_ * LQ * CIN_), oHI = nxt((size_t)B_ * LQ * CIN_);
  size_t oFF = nxt(0);
  // adaptive FFN row-chunk: biggest intermediate that fits the workspace
  int FCH = 2048;
  if ((oFF + (size_t)16384 * DFF_) * 4 <= ws_size)      FCH = 16384;
  else if ((oFF + (size_t)4096 * DFF_) * 4 <= ws_size)  FCH = 4096;
  (void)in_sizes; (void)n_in; (void)out_size;

  int* idxq = (int*)(ws + oIQ);
  int* idxk = (int*)(ws + oIK);

  auto GEMM = [&](const float* Ap, const float* Bp, const float* bias,
                  float* Cp, int Mr, int Nd, int Kd, int act) {
    dim3 g(Nd / 128, Mr / 128, 1);
    if (act) k_gemm<1><<<g, dim3(256), 0, stream>>>(Ap, Bp, bias, Cp, Mr, Nd, Kd);
    else     k_gemm<0><<<g, dim3(256), 0, stream>>>(Ap, Bp, bias, Cp, Mr, Nd, Kd);
  };
  // DFT+amp+topk; spectrum stored into scratch (one free BIG buffer)
  auto AMPSEL = [&](const float* x, float* scratch, int* idxp) {
    k_zero<<<2, 256, 0, stream>>>(ws + oAMP, 512);
    k_dftamp<<<dim3(128, 5), 256, 0, stream>>>(x, ws + oCOS, ws + oNSN,
        scratch, scratch + SPECH, ws + oNR, ws + oNI, ws + oAMP);
    k_topk<<<1, 512, 0, stream>>>(ws + oAMP, idxp);
  };
  auto GATHER = [&](const float* scratch, const int* idxp, float* gR, float* gI) {
    k_gathercols<<<4096, 256, 0, stream>>>(scratch, scratch + SPECH,
        ws + oNR, ws + oNI, idxp, gR, gI);
  };
  auto MODEMIX = [&](const float* sR, const float* sI, const float* wre, const float* wim) {
    k_modemix<<<dim3(16, H_, B_), dim3(64, 4), 0, stream>>>(sR, sI, wre, wim, ws + oOR, ws + oOI);
  };
  auto IRFFT = [&](const int* idxp, float scale, float* dst) {
    k_irfft<<<dim3(D_, B_), 512, 0, stream>>>(ws + oOR, ws + oOI, idxp,
                                              ws + oC5, ws + oS5, scale, dst);
  };
  auto DECOMP = [&](const float* a, const float* bsrc, float* season, float* trend, int mode) {
    k_decomp<<<dim3(D_ / 256, LQ / 64, B_), 256, 0, stream>>>(a, bsrc, season, trend, mode);
  };
  auto FFNP = [&](const float* x, const float* c1, const float* c2, float* y) {
    for (int ch = 0; ch < (B_ * LQ) / FCH; ch++) {
      GEMM(x + (size_t)ch * FCH * D_, c1, nullptr, ws + oFF, FCH, DFF_, D_, 1);
      GEMM(ws + oFF, c2, nullptr, y + (size_t)ch * FCH * D_, FCH, D_, DFF_, 0);
    }
  };

  // ---- prologue
  k_dft_tables<<<(512 * TW + 255) / 256, 256, 0, stream>>>(ws + oCOS, ws + oNSN,
                                                           ws + oC5, ws + oS5);
  k_enc_decomp<<<B_, 32, 0, stream>>>(x_enc, ws + oLOW, ws + oHI);
  k_embed<<<dim3(2, LQ, B_), 256, 0, stream>>>(x_enc, x_mark_enc, emb_enc_k, emb_enc_t, ws + oA);

  // ---- encoder (enc lives in A; temporaries B, C; C doubles as spectrum scratch)
  for (int i = 0; i < 2; i++) {
    GEMM(ws + oA, enc_Wq + (size_t)i * D_ * D_, enc_bq + (size_t)i * D_, ws + oB, B_ * LQ, D_, D_, 0);
    AMPSEL(ws + oB, ws + oC, idxq);
    GATHER(ws + oC, idxq, ws + oQSR, ws + oQSI);
    MODEMIX(ws + oQSR, ws + oQSI, fw_enc_re, fw_enc_im);
    IRFFT(idxq, 1.f / 512.f, ws + oB);
    GEMM(ws + oB, enc_Wo + (size_t)i * D_ * D_, enc_bo + (size_t)i * D_, ws + oC, B_ * LQ, D_, D_, 0);
    DECOMP(ws + oA, ws + oC, ws + oB, nullptr, 0);                       // x1 -> B
    FFNP(ws + oB, enc_c1 + (size_t)i * D_ * DFF_, enc_c2 + (size_t)i * DFF_ * D_, ws + oC);
    DECOMP(ws + oB, ws + oC, ws + oA, nullptr, 0);                       // enc -> A
  }
  k_ln<<<B_ * LQ, 256, 0, stream>>>(ws + oA, enc_ng, enc_nb, ws + oB);
  k_tmsub<<<dim3(2, B_), 256, 0, stream>>>(ws + oB, ws + oA);            // enc final -> A

  // ---- cross-K path (enc consumed by this GEMM; A then free)
  GEMM(ws + oA, dc_Wk, dc_bk, ws + oB, B_ * LQ, D_, D_, 0);
  AMPSEL(ws + oB, ws + oC, idxk);
  GATHER(ws + oC, idxk, ws + oKSR, ws + oKSI);

  // ---- decoder (dec -> A)
  k_embed<<<dim3(2, LQ, B_), 256, 0, stream>>>(ws + oHI, x_mark_dec, emb_dec_k, emb_dec_t, ws + oA);
  GEMM(ws + oA, ds_Wq, ds_bq, ws + oB, B_ * LQ, D_, D_, 0);
  AMPSEL(ws + oB, ws + oC, idxq);
  GATHER(ws + oC, idxq, ws + oQSR, ws + oQSI);
  MODEMIX(ws + oQSR, ws + oQSI, fw_dec_re, fw_dec_im);
  IRFFT(idxq, 1.f / 512.f, ws + oB);
  GEMM(ws + oB, ds_Wo, ds_bo, ws + oC, B_ * LQ, D_, D_, 0);              // a -> C
  DECOMP(ws + oA, ws + oC, ws + oB, ws + oTS, 1);                        // x1 -> B, t1 -> TS (A free)

  GEMM(ws + oB, dc_Wq, dc_bq, ws + oC, B_ * LQ, D_, D_, 0);              // q -> C
  AMPSEL(ws + oC, ws + oA, idxq);                                        // spectrum -> A
  GATHER(ws + oA, idxq, ws + oQSR, ws + oQSI);
  k_qk<<<dim3(4, H_, B_), dim3(64, 4), 0, stream>>>(
      ws + oQSR, ws + oQSI, ws + oKSR, ws + oKSI, ws + oQKR, ws + oQKI);
  k_qkv<<<dim3(16, H_, B_), dim3(64, 4), 0, stream>>>(
      ws + oQKR, ws + oQKI, ws + oKSR, ws + oKSI, ws + oQSR, ws + oQSI); // v -> qs bufs
  MODEMIX(ws + oQSR, ws + oQSI, fw_cr_re, fw_cr_im);
  IRFFT(idxq, 1.f / (512.f * 262144.f), ws + oC);
  GEMM(ws + oC, dc_Wo, dc_bo, ws + oA, B_ * LQ, D_, D_, 0);              // c -> A
  DECOMP(ws + oB, ws + oA, ws + oC, ws + oTS, 2);                        // x2 -> C, t2 +=
  FFNP(ws + oC, dec_c1, dec_c2, ws + oA);                                // y -> A
  DECOMP(ws + oC, ws + oA, ws + oB, ws + oTS, 2);                        // x3 -> B, t3 +=
  k_ln<<<B_ * LQ, 256, 0, stream>>>(ws + oB, dec_ng, dec_nb, ws + oA);
  k_tmsub<<<dim3(2, B_), 256, 0, stream>>>(ws + oA, ws + oC);            // ln3 -> C
  k_final<<<dim3(B_ * PRED_ / 8), dim3(32, 8), 0, stream>>>(
      ws + oLOW, ws + oTS, dec_tp, ws + oC, proj_W, proj_b, out);
}